// Round 1
// baseline (8383.778 us; speedup 1.0000x reference)
//
#include <hip/hip_runtime.h>
#include <hip/hip_bf16.h>
#include <math.h>

#define B 8
#define L 197
#define DM 192
#define DI 384
#define NS 16
#define RK 12
#define DEPTH_ 24
#define MROWS (B*L)   // 1576

__device__ __forceinline__ float siluf(float x) { return x / (1.f + expf(-x)); }

// ---------------------------------------------------------------------------
// Patch embedding: conv 16x16 stride 16 == per-patch 768->192 matvec.
// One block per (batch, position). Position 98 is the cls token.
// Also zero-initializes the residual stream.
// ---------------------------------------------------------------------------
__global__ __launch_bounds__(192)
void patch_embed_k(const float* __restrict__ x, const float* __restrict__ pw,
                   const float* __restrict__ pb, const float* __restrict__ cls,
                   const float* __restrict__ pos, float* __restrict__ hidden,
                   float* __restrict__ residual)
{
    int bp = blockIdx.x;
    int b = bp / L, p = bp % L;
    int c = threadIdx.x;
    __shared__ float patch[768];
    float v;
    if (p == 98) {
        v = cls[c];
    } else {
        int pi = p - (p > 98);
        int py = pi / 14, px = pi % 14;
        for (int e = c; e < 768; e += 192) {
            int ci = e >> 8, rem = e & 255, ky = rem >> 4, kx = rem & 15;
            patch[e] = x[(((size_t)b*3 + ci)*224 + py*16 + ky)*224 + px*16 + kx];
        }
        __syncthreads();
        float acc = pb[c];
        const float* w = pw + (size_t)c * 768;
        #pragma unroll 8
        for (int e = 0; e < 768; ++e) acc += w[e] * patch[e];
        v = acc;
    }
    v += pos[(size_t)p * DM + c];
    size_t off = (size_t)bp * DM + c;
    hidden[off] = v;
    residual[off] = 0.f;
}

// ---------------------------------------------------------------------------
// residual += hidden; xn = rmsnorm(residual) * nw.   One block per row.
// ---------------------------------------------------------------------------
__global__ __launch_bounds__(192)
void resid_rms_k(float* __restrict__ residual, const float* __restrict__ hidden,
                 const float* __restrict__ nw, float* __restrict__ xn)
{
    int row = blockIdx.x;
    int c = threadIdx.x;
    size_t off = (size_t)row * DM + c;
    float v = residual[off] + hidden[off];
    residual[off] = v;
    float s = v * v;
    #pragma unroll
    for (int o = 32; o; o >>= 1) s += __shfl_down(s, o);
    __shared__ float wsum[3];
    if ((c & 63) == 0) wsum[c >> 6] = s;
    __syncthreads();
    float total = wsum[0] + wsum[1] + wsum[2];
    float rs = rsqrtf(total * (1.f / DM) + 1e-5f);
    xn[off] = v * rs * nw[c];
}

// ---------------------------------------------------------------------------
// O[m,n] = sum_k X[m*ldx+k] * W[n*K+k]   (W row-major [N,K], i.e. X @ W^T)
// 64x64 block tile, BK=32, 256 threads, 4x4 per-thread tile.
// LDS stored k-major so the inner loop does two float4 reads per kk.
// K must be a multiple of 32 (192/384 here). M,N tails guarded.
// ---------------------------------------------------------------------------
__global__ __launch_bounds__(256)
void gemm_xwT(const float* __restrict__ X, int ldx,
              const float* __restrict__ W,
              float* __restrict__ O, int ldo,
              int M, int N, int K)
{
    __shared__ __align__(16) float Xs[32][68];
    __shared__ __align__(16) float Ws[32][68];
    const int bm = blockIdx.y * 64;
    const int bn = blockIdx.x * 64;
    const int tcol = threadIdx.x & 15;
    const int trow = threadIdx.x >> 4;
    float acc[4][4] = {};
    for (int k0 = 0; k0 < K; k0 += 32) {
        for (int i = threadIdx.x; i < 64 * 32; i += 256) {
            int r = i >> 5, c = i & 31;
            int gm = bm + r;
            Xs[c][r] = (gm < M) ? X[(size_t)gm * ldx + k0 + c] : 0.f;
        }
        for (int i = threadIdx.x; i < 64 * 32; i += 256) {
            int r = i >> 5, c = i & 31;
            int gn = bn + r;
            Ws[c][r] = (gn < N) ? W[(size_t)gn * K + k0 + c] : 0.f;
        }
        __syncthreads();
        #pragma unroll
        for (int kk = 0; kk < 32; ++kk) {
            float4 xv = *(const float4*)&Xs[kk][trow * 4];
            float4 wv = *(const float4*)&Ws[kk][tcol * 4];
            float xr[4] = {xv.x, xv.y, xv.z, xv.w};
            float wr[4] = {wv.x, wv.y, wv.z, wv.w};
            #pragma unroll
            for (int i = 0; i < 4; ++i)
                #pragma unroll
                for (int j = 0; j < 4; ++j) acc[i][j] += xr[i] * wr[j];
        }
        __syncthreads();
    }
    #pragma unroll
    for (int i = 0; i < 4; ++i) {
        int gm = bm + trow * 4 + i;
        if (gm >= M) continue;
        #pragma unroll
        for (int j = 0; j < 4; ++j) {
            int gn = bn + tcol * 4 + j;
            if (gn < N) O[(size_t)gm * ldo + gn] = acc[i][j];
        }
    }
}

// ---------------------------------------------------------------------------
// Depthwise causal conv1d (k=4, pad-left 3) + bias + silu.
// xz rows are [xi(384) | z(384)]; reads the xi half.
// ---------------------------------------------------------------------------
__global__ __launch_bounds__(256)
void conv_silu_k(const float* __restrict__ xz, const float* __restrict__ cw,
                 const float* __restrict__ cb, float* __restrict__ xc)
{
    int idx = blockIdx.x * 256 + threadIdx.x;
    if (idx >= MROWS * DI) return;
    int d = idx % DI;
    int row = idx / DI;
    int t = row % L;
    float acc = cb[d];
    #pragma unroll
    for (int j = 0; j < 4; ++j) {
        int tt = t - 3 + j;
        if (tt >= 0) acc += xz[(size_t)(row - (3 - j)) * (2 * DI) + d] * cw[d * 4 + j];
    }
    xc[idx] = siluf(acc);
}

// ---------------------------------------------------------------------------
// dt = softplus(x_dbl[:, :12] @ dtw^T + dtb)
// ---------------------------------------------------------------------------
__global__ __launch_bounds__(256)
void dtproj_k(const float* __restrict__ xdbl, const float* __restrict__ dtw,
              const float* __restrict__ dtbias, float* __restrict__ dt)
{
    int idx = blockIdx.x * 256 + threadIdx.x;
    if (idx >= MROWS * DI) return;
    int d = idx % DI;
    int row = idx / DI;
    const float* xr = xdbl + (size_t)row * 44;
    const float* wr = dtw + d * RK;
    float acc = dtbias[d];
    #pragma unroll
    for (int k = 0; k < RK; ++k) acc += xr[k] * wr[k];
    dt[idx] = (acc > 20.f) ? acc : log1pf(expf(acc));
}

// ---------------------------------------------------------------------------
// Selective scan. Thread layout: lane = n (16) x d-local (16); block covers
// (batch, 16 channels). Recurrence h = exp(dt*A)*h + dt*u*B is independent
// per (b,d,n); y needs a 16-lane reduction over n. Output is gated:
// yg = (y + u*D) * silu(z).
// ---------------------------------------------------------------------------
__global__ __launch_bounds__(256)
void scan_k(const float* __restrict__ dt, const float* __restrict__ xc,
            const float* __restrict__ xz, const float* __restrict__ xdbl,
            const float* __restrict__ Alog, const float* __restrict__ Dp,
            float* __restrict__ yg)
{
    int blk = blockIdx.x;             // b * (DI/16) + dc
    int b = blk / (DI / 16);
    int dc = blk % (DI / 16);
    int nl = threadIdx.x & 15;
    int dl = threadIdx.x >> 4;
    int d = dc * 16 + dl;
    float Acoef = -expf(Alog[d * NS + nl]);
    float Dv = Dp[d];
    float h = 0.f;
    int row = b * L;
    for (int t = 0; t < L; ++t, ++row) {
        float dtv = dt[(size_t)row * DI + d];
        float u   = xc[(size_t)row * DI + d];
        float Bv  = xdbl[(size_t)row * 44 + 12 + nl];
        float Cv  = xdbl[(size_t)row * 44 + 28 + nl];
        float dA = expf(dtv * Acoef);
        h = dA * h + (dtv * u) * Bv;
        float p = h * Cv;
        p += __shfl_xor(p, 8, 16);
        p += __shfl_xor(p, 4, 16);
        p += __shfl_xor(p, 2, 16);
        p += __shfl_xor(p, 1, 16);
        if (nl == 0) {
            float z = xz[(size_t)row * (2 * DI) + DI + d];
            yg[(size_t)row * DI + d] = (p + u * Dv) * siluf(z);
        }
    }
}

// ---------------------------------------------------------------------------
// Final: rmsnorm(hidden + residual) at cls row (pos 98) then head GEMV.
// One block per batch.
// ---------------------------------------------------------------------------
__global__ __launch_bounds__(256)
void final_head_k(const float* __restrict__ hidden, const float* __restrict__ residual,
                  const float* __restrict__ nfw, const float* __restrict__ hw,
                  const float* __restrict__ hb, float* __restrict__ out)
{
    int b = blockIdx.x;
    int tid = threadIdx.x;
    __shared__ float rowv[DM];
    __shared__ float wsum[4];
    size_t off = ((size_t)b * L + 98) * DM;
    float v = 0.f;
    if (tid < DM) v = hidden[off + tid] + residual[off + tid];
    float s = v * v;
    #pragma unroll
    for (int o = 32; o; o >>= 1) s += __shfl_down(s, o);
    if ((tid & 63) == 0) wsum[tid >> 6] = s;
    __syncthreads();
    float total = wsum[0] + wsum[1] + wsum[2] + wsum[3];
    float rs = rsqrtf(total * (1.f / DM) + 1e-5f);
    if (tid < DM) rowv[tid] = v * rs * nfw[tid];
    __syncthreads();
    for (int o = tid; o < 1000; o += 256) {
        float acc = hb[o];
        const float* w = hw + (size_t)o * DM;
        #pragma unroll 8
        for (int k = 0; k < DM; ++k) acc += w[k] * rowv[k];
        out[(size_t)b * 1000 + o] = acc;
    }
}

// ---------------------------------------------------------------------------
extern "C" void kernel_launch(void* const* d_in, const int* in_sizes, int n_in,
                              void* d_out, int out_size, void* d_ws, size_t ws_size,
                              hipStream_t stream)
{
    const float* x        = (const float*)d_in[0];
    const float* patch_w  = (const float*)d_in[1];
    const float* patch_b  = (const float*)d_in[2];
    const float* cls_tok  = (const float*)d_in[3];
    const float* pos_emb  = (const float*)d_in[4];
    const float* norm_w   = (const float*)d_in[5];
    const float* in_w     = (const float*)d_in[6];
    const float* conv_w   = (const float*)d_in[7];
    const float* conv_b   = (const float*)d_in[8];
    const float* xproj_w  = (const float*)d_in[9];
    const float* dt_w     = (const float*)d_in[10];
    const float* dt_b     = (const float*)d_in[11];
    const float* A_log    = (const float*)d_in[12];
    const float* D_par    = (const float*)d_in[13];
    const float* out_w    = (const float*)d_in[14];
    const float* norm_fw  = (const float*)d_in[15];
    const float* head_w   = (const float*)d_in[16];
    const float* head_b   = (const float*)d_in[17];

    float* ws = (float*)d_ws;
    float* hidden   = ws;  ws += (size_t)MROWS * DM;
    float* residual = ws;  ws += (size_t)MROWS * DM;
    float* xn       = ws;  ws += (size_t)MROWS * DM;
    float* xzb      = ws;  ws += (size_t)MROWS * 2 * DI;
    float* xcb      = ws;  ws += (size_t)MROWS * DI;
    float* xdb      = ws;  ws += (size_t)MROWS * 44;
    float* dtb_     = ws;  ws += (size_t)MROWS * DI;
    float* ygb      = ws;  ws += (size_t)MROWS * DI;

    patch_embed_k<<<B * L, DM, 0, stream>>>(x, patch_w, patch_b, cls_tok, pos_emb,
                                            hidden, residual);

    const int eltBlocks = (MROWS * DI + 255) / 256;
    for (int l = 0; l < DEPTH_; ++l) {
        resid_rms_k<<<MROWS, DM, 0, stream>>>(residual, hidden, norm_w + l * DM, xn);
        // xz = xn @ in_w^T      [1576,192] x [768,192]^T
        gemm_xwT<<<dim3(12, 25), 256, 0, stream>>>(xn, DM, in_w + (size_t)l * 2 * DI * DM,
                                                   xzb, 2 * DI, MROWS, 2 * DI, DM);
        conv_silu_k<<<eltBlocks, 256, 0, stream>>>(xzb, conv_w + l * DI * 4,
                                                   conv_b + l * DI, xcb);
        // x_dbl = xc @ xproj_w^T   [1576,384] x [44,384]^T
        gemm_xwT<<<dim3(1, 25), 256, 0, stream>>>(xcb, DI, xproj_w + (size_t)l * 44 * DI,
                                                  xdb, 44, MROWS, 44, DI);
        dtproj_k<<<eltBlocks, 256, 0, stream>>>(xdb, dt_w + l * DI * RK, dt_b + l * DI, dtb_);
        scan_k<<<B * (DI / 16), 256, 0, stream>>>(dtb_, xcb, xzb, xdb,
                                                  A_log + (size_t)l * DI * NS,
                                                  D_par + l * DI, ygb);
        // hidden = yg @ out_w^T   [1576,384] x [192,384]^T
        gemm_xwT<<<dim3(3, 25), 256, 0, stream>>>(ygb, DI, out_w + (size_t)l * DM * DI,
                                                  hidden, DM, MROWS, DM, DI);
    }
    final_head_k<<<B, 256, 0, stream>>>(hidden, residual, norm_fw, head_w, head_b,
                                        (float*)d_out);
}

// Round 2
// 5909.722 us; speedup vs baseline: 1.4186x; 1.4186x over previous
//
#include <hip/hip_runtime.h>
#include <hip/hip_bf16.h>
#include <math.h>

#define B 8
#define L 197
#define DM 192
#define DI 384
#define NS 16
#define RK 12
#define DEPTH_ 24
#define MROWS (B*L)   // 1576

__device__ __forceinline__ float siluf(float x) { return x / (1.f + expf(-x)); }

// ---------------------------------------------------------------------------
// Patch embedding: conv 16x16 stride 16 == per-patch 768->192 matvec.
// One block per (batch, position). Position 98 is the cls token.
// Also zero-initializes the residual stream.
// ---------------------------------------------------------------------------
__global__ __launch_bounds__(192)
void patch_embed_k(const float* __restrict__ x, const float* __restrict__ pw,
                   const float* __restrict__ pb, const float* __restrict__ cls,
                   const float* __restrict__ pos, float* __restrict__ hidden,
                   float* __restrict__ residual)
{
    int bp = blockIdx.x;
    int b = bp / L, p = bp % L;
    int c = threadIdx.x;
    __shared__ float patch[768];
    float v;
    if (p == 98) {
        v = cls[c];
    } else {
        int pi = p - (p > 98);
        int py = pi / 14, px = pi % 14;
        for (int e = c; e < 768; e += 192) {
            int ci = e >> 8, rem = e & 255, ky = rem >> 4, kx = rem & 15;
            patch[e] = x[(((size_t)b*3 + ci)*224 + py*16 + ky)*224 + px*16 + kx];
        }
        __syncthreads();
        float acc = pb[c];
        const float* w = pw + (size_t)c * 768;
        #pragma unroll 8
        for (int e = 0; e < 768; ++e) acc += w[e] * patch[e];
        v = acc;
    }
    v += pos[(size_t)p * DM + c];
    size_t off = (size_t)bp * DM + c;
    hidden[off] = v;
    residual[off] = 0.f;
}

// ---------------------------------------------------------------------------
// residual += hidden; xn = rmsnorm(residual) * nw.   One block per row.
// ---------------------------------------------------------------------------
__global__ __launch_bounds__(192)
void resid_rms_k(float* __restrict__ residual, const float* __restrict__ hidden,
                 const float* __restrict__ nw, float* __restrict__ xn)
{
    int row = blockIdx.x;
    int c = threadIdx.x;
    size_t off = (size_t)row * DM + c;
    float v = residual[off] + hidden[off];
    residual[off] = v;
    float s = v * v;
    #pragma unroll
    for (int o = 32; o; o >>= 1) s += __shfl_down(s, o);
    __shared__ float wsum[3];
    if ((c & 63) == 0) wsum[c >> 6] = s;
    __syncthreads();
    float total = wsum[0] + wsum[1] + wsum[2];
    float rs = rsqrtf(total * (1.f / DM) + 1e-5f);
    xn[off] = v * rs * nw[c];
}

// ---------------------------------------------------------------------------
// O[m,n] = sum_k X[m*ldx+k] * W[n*K+k]   (W row-major [N,K], i.e. X @ W^T)
// 64x64 block tile, BK=32, 256 threads, 4x4 per-thread tile.
// ---------------------------------------------------------------------------
__global__ __launch_bounds__(256)
void gemm_xwT(const float* __restrict__ X, int ldx,
              const float* __restrict__ W,
              float* __restrict__ O, int ldo,
              int M, int N, int K)
{
    __shared__ __align__(16) float Xs[32][68];
    __shared__ __align__(16) float Ws[32][68];
    const int bm = blockIdx.y * 64;
    const int bn = blockIdx.x * 64;
    const int tcol = threadIdx.x & 15;
    const int trow = threadIdx.x >> 4;
    float acc[4][4] = {};
    for (int k0 = 0; k0 < K; k0 += 32) {
        for (int i = threadIdx.x; i < 64 * 32; i += 256) {
            int r = i >> 5, c = i & 31;
            int gm = bm + r;
            Xs[c][r] = (gm < M) ? X[(size_t)gm * ldx + k0 + c] : 0.f;
        }
        for (int i = threadIdx.x; i < 64 * 32; i += 256) {
            int r = i >> 5, c = i & 31;
            int gn = bn + r;
            Ws[c][r] = (gn < N) ? W[(size_t)gn * K + k0 + c] : 0.f;
        }
        __syncthreads();
        #pragma unroll
        for (int kk = 0; kk < 32; ++kk) {
            float4 xv = *(const float4*)&Xs[kk][trow * 4];
            float4 wv = *(const float4*)&Ws[kk][tcol * 4];
            float xr[4] = {xv.x, xv.y, xv.z, xv.w};
            float wr[4] = {wv.x, wv.y, wv.z, wv.w};
            #pragma unroll
            for (int i = 0; i < 4; ++i)
                #pragma unroll
                for (int j = 0; j < 4; ++j) acc[i][j] += xr[i] * wr[j];
        }
        __syncthreads();
    }
    #pragma unroll
    for (int i = 0; i < 4; ++i) {
        int gm = bm + trow * 4 + i;
        if (gm >= M) continue;
        #pragma unroll
        for (int j = 0; j < 4; ++j) {
            int gn = bn + tcol * 4 + j;
            if (gn < N) O[(size_t)gm * ldo + gn] = acc[i][j];
        }
    }
}

// ---------------------------------------------------------------------------
// Depthwise causal conv1d (k=4, pad-left 3) + bias + silu.
// xz rows are [xi(384) | z(384)]; reads the xi half.
// ---------------------------------------------------------------------------
__global__ __launch_bounds__(256)
void conv_silu_k(const float* __restrict__ xz, const float* __restrict__ cw,
                 const float* __restrict__ cb, float* __restrict__ xc)
{
    int idx = blockIdx.x * 256 + threadIdx.x;
    if (idx >= MROWS * DI) return;
    int d = idx % DI;
    int row = idx / DI;
    int t = row % L;
    float acc = cb[d];
    #pragma unroll
    for (int j = 0; j < 4; ++j) {
        int tt = t - 3 + j;
        if (tt >= 0) acc += xz[(size_t)(row - (3 - j)) * (2 * DI) + d] * cw[d * 4 + j];
    }
    xc[idx] = siluf(acc);
}

// ---------------------------------------------------------------------------
// Fused dt_proj + selective scan, LDS-staged.
// Block = (batch b, 16-channel group dc). 256 threads = 16 d x 16 n.
// Phase 1 (cooperative, coalesced): stage B,C,u into LDS; compute
//   dt = softplus(x_dbl[:, :12] @ dtw^T + dtb) into LDS.
// Phase 2: serial scan over t from LDS. h-chain is 1 FMA/step; all LDS
//   reads are independent across steps -> unroll pipelines them.
// Phase 3 (cooperative): gate with silu(z) and write coalesced.
// LDS = 5 * 197*16*4 = 63,040 B (under 64 KB static limit).
// ---------------------------------------------------------------------------
__global__ __launch_bounds__(256)
void scan_fused_k(const float* __restrict__ xdbl, const float* __restrict__ xc,
                  const float* __restrict__ xz, const float* __restrict__ dtw,
                  const float* __restrict__ dtbias, const float* __restrict__ Alog,
                  const float* __restrict__ Dp, float* __restrict__ yg)
{
    __shared__ float sdt[L * 16];
    __shared__ float su [L * 16];
    __shared__ float sB [L * 16];
    __shared__ float sC [L * 16];
    __shared__ float sy [L * 16];

    const int blk = blockIdx.x;           // b * 24 + dc
    const int b = blk / (DI / 16);
    const int dc = blk % (DI / 16);
    const int tid = threadIdx.x;

    for (int idx = tid; idx < L * 16; idx += 256) {
        int t = idx >> 4, c = idx & 15;
        size_t row = (size_t)(b * L + t);
        const float* xr = xdbl + row * 44;
        sB[idx] = xr[12 + c];
        sC[idx] = xr[28 + c];
        su[idx] = xc[row * DI + dc * 16 + c];
        int d = dc * 16 + c;
        const float* wr = dtw + d * RK;
        float acc = dtbias[d];
        #pragma unroll
        for (int k = 0; k < RK; ++k) acc += xr[k] * wr[k];
        sdt[idx] = (acc > 20.f) ? acc : log1pf(expf(acc));
    }
    __syncthreads();

    const int nl = tid & 15;
    const int dl = tid >> 4;
    const int d = dc * 16 + dl;
    const float Acoef = -expf(Alog[d * NS + nl]);
    const float Dv = Dp[d];
    float h = 0.f;
    #pragma unroll 4
    for (int t = 0; t < L; ++t) {
        float dtv = sdt[t * 16 + dl];
        float u   = su [t * 16 + dl];
        float Bv  = sB [t * 16 + nl];
        float Cv  = sC [t * 16 + nl];
        float dA = expf(dtv * Acoef);
        h = dA * h + (dtv * u) * Bv;
        float p = h * Cv;
        p += __shfl_xor(p, 8, 16);
        p += __shfl_xor(p, 4, 16);
        p += __shfl_xor(p, 2, 16);
        p += __shfl_xor(p, 1, 16);
        if (nl == 0) sy[t * 16 + dl] = p + u * Dv;
    }
    __syncthreads();

    for (int idx = tid; idx < L * 16; idx += 256) {
        int t = idx >> 4, c = idx & 15;
        size_t row = (size_t)(b * L + t);
        float z = xz[row * (2 * DI) + DI + dc * 16 + c];
        yg[row * DI + dc * 16 + c] = sy[idx] * siluf(z);
    }
}

// ---------------------------------------------------------------------------
// Final: rmsnorm(hidden + residual) at cls row (pos 98) then head GEMV.
// One block per batch.
// ---------------------------------------------------------------------------
__global__ __launch_bounds__(256)
void final_head_k(const float* __restrict__ hidden, const float* __restrict__ residual,
                  const float* __restrict__ nfw, const float* __restrict__ hw,
                  const float* __restrict__ hb, float* __restrict__ out)
{
    int b = blockIdx.x;
    int tid = threadIdx.x;
    __shared__ float rowv[DM];
    __shared__ float wsum[4];
    size_t off = ((size_t)b * L + 98) * DM;
    float v = 0.f;
    if (tid < DM) v = hidden[off + tid] + residual[off + tid];
    float s = v * v;
    #pragma unroll
    for (int o = 32; o; o >>= 1) s += __shfl_down(s, o);
    if ((tid & 63) == 0) wsum[tid >> 6] = s;
    __syncthreads();
    float total = wsum[0] + wsum[1] + wsum[2] + wsum[3];
    float rs = rsqrtf(total * (1.f / DM) + 1e-5f);
    if (tid < DM) rowv[tid] = v * rs * nfw[tid];
    __syncthreads();
    for (int o = tid; o < 1000; o += 256) {
        float acc = hb[o];
        const float* w = hw + (size_t)o * DM;
        #pragma unroll 8
        for (int k = 0; k < DM; ++k) acc += w[k] * rowv[k];
        out[(size_t)b * 1000 + o] = acc;
    }
}

// ---------------------------------------------------------------------------
extern "C" void kernel_launch(void* const* d_in, const int* in_sizes, int n_in,
                              void* d_out, int out_size, void* d_ws, size_t ws_size,
                              hipStream_t stream)
{
    const float* x        = (const float*)d_in[0];
    const float* patch_w  = (const float*)d_in[1];
    const float* patch_b  = (const float*)d_in[2];
    const float* cls_tok  = (const float*)d_in[3];
    const float* pos_emb  = (const float*)d_in[4];
    const float* norm_w   = (const float*)d_in[5];
    const float* in_w     = (const float*)d_in[6];
    const float* conv_w   = (const float*)d_in[7];
    const float* conv_b   = (const float*)d_in[8];
    const float* xproj_w  = (const float*)d_in[9];
    const float* dt_w     = (const float*)d_in[10];
    const float* dt_b     = (const float*)d_in[11];
    const float* A_log    = (const float*)d_in[12];
    const float* D_par    = (const float*)d_in[13];
    const float* out_w    = (const float*)d_in[14];
    const float* norm_fw  = (const float*)d_in[15];
    const float* head_w   = (const float*)d_in[16];
    const float* head_b   = (const float*)d_in[17];

    float* ws = (float*)d_ws;
    float* hidden   = ws;  ws += (size_t)MROWS * DM;
    float* residual = ws;  ws += (size_t)MROWS * DM;
    float* xn       = ws;  ws += (size_t)MROWS * DM;
    float* xzb      = ws;  ws += (size_t)MROWS * 2 * DI;
    float* xcb      = ws;  ws += (size_t)MROWS * DI;
    float* xdb      = ws;  ws += (size_t)MROWS * 44;
    float* ygb      = ws;  ws += (size_t)MROWS * DI;

    patch_embed_k<<<B * L, DM, 0, stream>>>(x, patch_w, patch_b, cls_tok, pos_emb,
                                            hidden, residual);

    const int eltBlocks = (MROWS * DI + 255) / 256;
    for (int l = 0; l < DEPTH_; ++l) {
        resid_rms_k<<<MROWS, DM, 0, stream>>>(residual, hidden, norm_w + l * DM, xn);
        // xz = xn @ in_w^T      [1576,192] x [768,192]^T
        gemm_xwT<<<dim3(12, 25), 256, 0, stream>>>(xn, DM, in_w + (size_t)l * 2 * DI * DM,
                                                   xzb, 2 * DI, MROWS, 2 * DI, DM);
        conv_silu_k<<<eltBlocks, 256, 0, stream>>>(xzb, conv_w + l * DI * 4,
                                                   conv_b + l * DI, xcb);
        // x_dbl = xc @ xproj_w^T   [1576,384] x [44,384]^T
        gemm_xwT<<<dim3(1, 25), 256, 0, stream>>>(xcb, DI, xproj_w + (size_t)l * 44 * DI,
                                                  xdb, 44, MROWS, 44, DI);
        scan_fused_k<<<B * (DI / 16), 256, 0, stream>>>(xdb, xcb, xzb,
                                                        dt_w + (size_t)l * DI * RK,
                                                        dt_b + l * DI,
                                                        A_log + (size_t)l * DI * NS,
                                                        D_par + l * DI, ygb);
        // hidden = yg @ out_w^T   [1576,384] x [192,384]^T
        gemm_xwT<<<dim3(3, 25), 256, 0, stream>>>(ygb, DI, out_w + (size_t)l * DM * DI,
                                                  hidden, DM, MROWS, DM, DI);
    }
    final_head_k<<<B, 256, 0, stream>>>(hidden, residual, norm_fw, head_w, head_b,
                                        (float*)d_out);
}

// Round 3
// 4828.836 us; speedup vs baseline: 1.7362x; 1.2238x over previous
//
#include <hip/hip_runtime.h>
#include <hip/hip_bf16.h>
#include <math.h>

#define B 8
#define L 197
#define DM 192
#define DI 384
#define NS 16
#define RK 12
#define DEPTH_ 24
#define MROWS (B*L)   // 1576

typedef __bf16 bf16x8 __attribute__((ext_vector_type(8)));
typedef float  f32x4  __attribute__((ext_vector_type(4)));

__device__ __forceinline__ float siluf(float x) { return x / (1.f + expf(-x)); }

// ===========================================================================
// MFMA tile geometry (all GEMM kernels): 256 threads = 4 waves (2x2), block
// tile 64x64, per-wave 32x32 via 2x2 frags of mfma_f32_16x16x32_bf16.
// A,B staged row-major k-contiguous in LDS (pad keeps b128 reads ~2-way).
// Frag load: row = lane&15, k = (lane>>4)*8.  D: col = lane&15,
// row = (lane>>4)*4 + reg  [m89-verified mapping].
// ===========================================================================

// ---------------------------------------------------------------------------
// Patch embed as GEMM: [1568 patches, 768] @ patch_w[192,768]^T, epilogue adds
// patch_b + pos_embed and scatters into the residual stream (skipping the cls
// slot at position 98). grid (3, 25).
// ---------------------------------------------------------------------------
__global__ __launch_bounds__(256)
void patch_gemm_k(const float* __restrict__ x, const float* __restrict__ pw,
                  const float* __restrict__ pb, const float* __restrict__ pos,
                  float* __restrict__ residual)
{
    __shared__ __bf16 Xs[64][136];
    __shared__ __bf16 Ws[64][136];
    const int bm = blockIdx.y * 64;
    const int bn = blockIdx.x * 64;
    const int tid = threadIdx.x;
    const int lane = tid & 63, wv = tid >> 6;
    const int wm = (wv >> 1) * 32, wn = (wv & 1) * 32;
    const int lr = lane & 15, lk = (lane >> 4) * 8;
    f32x4 acc[2][2] = {};
    for (int k0 = 0; k0 < 768; k0 += 128) {
        for (int i = tid; i < 64 * 32; i += 256) {
            int r = i >> 5, k4 = (i & 31) * 4;
            int gm = bm + r;
            float4 v = {0.f, 0.f, 0.f, 0.f};
            if (gm < 1568) {
                int b = gm / 196, f = gm % 196;
                int py = f / 14, px = f % 14;
                int k = k0 + k4;
                int ci = k >> 8, rem = k & 255, ky = rem >> 4, kx = rem & 15;
                v = *(const float4*)&x[(((size_t)b * 3 + ci) * 224 + py * 16 + ky) * 224 + px * 16 + kx];
            }
            Xs[r][k4+0] = (__bf16)v.x; Xs[r][k4+1] = (__bf16)v.y;
            Xs[r][k4+2] = (__bf16)v.z; Xs[r][k4+3] = (__bf16)v.w;
        }
        for (int i = tid; i < 64 * 32; i += 256) {
            int r = i >> 5, k4 = (i & 31) * 4;
            float4 v = *(const float4*)&pw[(size_t)(bn + r) * 768 + k0 + k4];
            Ws[r][k4+0] = (__bf16)v.x; Ws[r][k4+1] = (__bf16)v.y;
            Ws[r][k4+2] = (__bf16)v.z; Ws[r][k4+3] = (__bf16)v.w;
        }
        __syncthreads();
        #pragma unroll
        for (int ks = 0; ks < 128; ks += 32) {
            bf16x8 a0 = *(const bf16x8*)&Xs[wm + lr][ks + lk];
            bf16x8 a1 = *(const bf16x8*)&Xs[wm + 16 + lr][ks + lk];
            bf16x8 b0 = *(const bf16x8*)&Ws[wn + lr][ks + lk];
            bf16x8 b1 = *(const bf16x8*)&Ws[wn + 16 + lr][ks + lk];
            acc[0][0] = __builtin_amdgcn_mfma_f32_16x16x32_bf16(a0, b0, acc[0][0], 0, 0, 0);
            acc[0][1] = __builtin_amdgcn_mfma_f32_16x16x32_bf16(a0, b1, acc[0][1], 0, 0, 0);
            acc[1][0] = __builtin_amdgcn_mfma_f32_16x16x32_bf16(a1, b0, acc[1][0], 0, 0, 0);
            acc[1][1] = __builtin_amdgcn_mfma_f32_16x16x32_bf16(a1, b1, acc[1][1], 0, 0, 0);
        }
        __syncthreads();
    }
    #pragma unroll
    for (int i = 0; i < 2; ++i) {
        #pragma unroll
        for (int q = 0; q < 4; ++q) {
            int gm = bm + wm + i * 16 + (lane >> 4) * 4 + q;
            if (gm >= 1568) continue;
            int b = gm / 196, f = gm % 196;
            int p = f + (f >= 98);
            #pragma unroll
            for (int j = 0; j < 2; ++j) {
                int gn = bn + wn + j * 16 + (lane & 15);
                residual[((size_t)b * L + p) * DM + gn] =
                    acc[i][j][q] + pb[gn] + pos[(size_t)p * DM + gn];
            }
        }
    }
}

__global__ __launch_bounds__(192)
void cls_pos_k(const float* __restrict__ cls, const float* __restrict__ pos,
               float* __restrict__ residual)
{
    int c = threadIdx.x;
    float v = cls[c] + pos[98 * DM + c];
    for (int b = 0; b < B; ++b)
        residual[((size_t)b * L + 98) * DM + c] = v;
}

// ---------------------------------------------------------------------------
// gemm1: xz = rmsnorm(residual)*nw @ in_w^T   [1576,192]x[768,192]^T.
// fp32 row sumsq prologue, bf16 staging of the normalized row. grid (12, 25).
// ---------------------------------------------------------------------------
__global__ __launch_bounds__(256)
void gemm1_rms_k(const float* __restrict__ residual, const float* __restrict__ nw,
                 const float* __restrict__ W, float* __restrict__ O)
{
    __shared__ __bf16 Xs[64][200];
    __shared__ __bf16 Ws[64][200];
    __shared__ float sinv[64];
    const int bm = blockIdx.y * 64;
    const int bn = blockIdx.x * 64;
    const int tid = threadIdx.x;
    const int lane = tid & 63, wv = tid >> 6;
    const int wm = (wv >> 1) * 32, wn = (wv & 1) * 32;
    const int lr = lane & 15, lk = (lane >> 4) * 8;
    {   // per-row inv rms: 4 threads/row, float4 interleaved
        int r = tid >> 2, q = tid & 3;
        int gm = bm + r;
        float s = 0.f;
        if (gm < MROWS) {
            const float4* xr = (const float4*)(residual + (size_t)gm * DM);
            #pragma unroll
            for (int i = 0; i < 12; ++i) {
                float4 v = xr[q + i * 4];
                s += v.x*v.x + v.y*v.y + v.z*v.z + v.w*v.w;
            }
        }
        s += __shfl_xor(s, 1, 4);
        s += __shfl_xor(s, 2, 4);
        if (q == 0) sinv[r] = rsqrtf(s * (1.f / DM) + 1e-5f);
    }
    __syncthreads();
    for (int i = tid; i < 64 * 48; i += 256) {
        int r = i / 48, k4 = (i % 48) * 4;
        int gm = bm + r;
        float4 v = {0.f, 0.f, 0.f, 0.f};
        if (gm < MROWS) v = *(const float4*)&residual[(size_t)gm * DM + k4];
        float sc = sinv[r];
        float4 w4 = *(const float4*)&nw[k4];
        Xs[r][k4+0] = (__bf16)(v.x * sc * w4.x);
        Xs[r][k4+1] = (__bf16)(v.y * sc * w4.y);
        Xs[r][k4+2] = (__bf16)(v.z * sc * w4.z);
        Xs[r][k4+3] = (__bf16)(v.w * sc * w4.w);
    }
    for (int i = tid; i < 64 * 48; i += 256) {
        int r = i / 48, k4 = (i % 48) * 4;
        float4 v = *(const float4*)&W[(size_t)(bn + r) * DM + k4];
        Ws[r][k4+0] = (__bf16)v.x; Ws[r][k4+1] = (__bf16)v.y;
        Ws[r][k4+2] = (__bf16)v.z; Ws[r][k4+3] = (__bf16)v.w;
    }
    __syncthreads();
    f32x4 acc[2][2] = {};
    #pragma unroll
    for (int ks = 0; ks < 192; ks += 32) {
        bf16x8 a0 = *(const bf16x8*)&Xs[wm + lr][ks + lk];
        bf16x8 a1 = *(const bf16x8*)&Xs[wm + 16 + lr][ks + lk];
        bf16x8 b0 = *(const bf16x8*)&Ws[wn + lr][ks + lk];
        bf16x8 b1 = *(const bf16x8*)&Ws[wn + 16 + lr][ks + lk];
        acc[0][0] = __builtin_amdgcn_mfma_f32_16x16x32_bf16(a0, b0, acc[0][0], 0, 0, 0);
        acc[0][1] = __builtin_amdgcn_mfma_f32_16x16x32_bf16(a0, b1, acc[0][1], 0, 0, 0);
        acc[1][0] = __builtin_amdgcn_mfma_f32_16x16x32_bf16(a1, b0, acc[1][0], 0, 0, 0);
        acc[1][1] = __builtin_amdgcn_mfma_f32_16x16x32_bf16(a1, b1, acc[1][1], 0, 0, 0);
    }
    #pragma unroll
    for (int i = 0; i < 2; ++i)
        #pragma unroll
        for (int q = 0; q < 4; ++q) {
            int gm = bm + wm + i * 16 + (lane >> 4) * 4 + q;
            if (gm >= MROWS) continue;
            #pragma unroll
            for (int j = 0; j < 2; ++j) {
                int gn = bn + wn + j * 16 + (lane & 15);
                O[(size_t)gm * (2 * DI) + gn] = acc[i][j][q];
            }
        }
}

// ---------------------------------------------------------------------------
// gemm2: x_dbl = silu(conv(xi)+cb) @ x_proj_w^T. Single N-tile (44->64 pad),
// so every xc element is staged exactly once -> also written to xc for the
// scan. Conv in fp32 during staging. grid (25).
// ---------------------------------------------------------------------------
__global__ __launch_bounds__(256)
void gemm2_conv_k(const float* __restrict__ xz, const float* __restrict__ cw,
                  const float* __restrict__ cb, const float* __restrict__ W,
                  float* __restrict__ xc, float* __restrict__ O)
{
    __shared__ __bf16 Xs[64][136];
    __shared__ __bf16 Ws[64][136];
    const int bm = blockIdx.x * 64;
    const int tid = threadIdx.x;
    const int lane = tid & 63, wv = tid >> 6;
    const int wm = (wv >> 1) * 32, wn = (wv & 1) * 32;
    const int lr = lane & 15, lk = (lane >> 4) * 8;
    f32x4 acc[2][2] = {};
    for (int k0 = 0; k0 < DI; k0 += 128) {
        for (int i = tid; i < 64 * 128; i += 256) {
            int r = i >> 7, dk = i & 127;
            int gm = bm + r;
            float val = 0.f;
            if (gm < MROWS) {
                int d = k0 + dk;
                int t = gm % L;
                float a = cb[d];
                #pragma unroll
                for (int j = 0; j < 4; ++j) {
                    int tt = t - 3 + j;
                    if (tt >= 0) a += xz[(size_t)(gm - 3 + j) * (2 * DI) + d] * cw[d * 4 + j];
                }
                val = siluf(a);
                xc[(size_t)gm * DI + d] = val;
            }
            Xs[r][dk] = (__bf16)val;
        }
        for (int i = tid; i < 64 * 32; i += 256) {
            int r = i >> 5, k4 = (i & 31) * 4;
            float4 v = {0.f, 0.f, 0.f, 0.f};
            if (r < 44) v = *(const float4*)&W[(size_t)r * DI + k0 + k4];
            Ws[r][k4+0] = (__bf16)v.x; Ws[r][k4+1] = (__bf16)v.y;
            Ws[r][k4+2] = (__bf16)v.z; Ws[r][k4+3] = (__bf16)v.w;
        }
        __syncthreads();
        #pragma unroll
        for (int ks = 0; ks < 128; ks += 32) {
            bf16x8 a0 = *(const bf16x8*)&Xs[wm + lr][ks + lk];
            bf16x8 a1 = *(const bf16x8*)&Xs[wm + 16 + lr][ks + lk];
            bf16x8 b0 = *(const bf16x8*)&Ws[wn + lr][ks + lk];
            bf16x8 b1 = *(const bf16x8*)&Ws[wn + 16 + lr][ks + lk];
            acc[0][0] = __builtin_amdgcn_mfma_f32_16x16x32_bf16(a0, b0, acc[0][0], 0, 0, 0);
            acc[0][1] = __builtin_amdgcn_mfma_f32_16x16x32_bf16(a0, b1, acc[0][1], 0, 0, 0);
            acc[1][0] = __builtin_amdgcn_mfma_f32_16x16x32_bf16(a1, b0, acc[1][0], 0, 0, 0);
            acc[1][1] = __builtin_amdgcn_mfma_f32_16x16x32_bf16(a1, b1, acc[1][1], 0, 0, 0);
        }
        __syncthreads();
    }
    #pragma unroll
    for (int i = 0; i < 2; ++i)
        #pragma unroll
        for (int q = 0; q < 4; ++q) {
            int gm = bm + wm + i * 16 + (lane >> 4) * 4 + q;
            if (gm >= MROWS) continue;
            #pragma unroll
            for (int j = 0; j < 2; ++j) {
                int gn = wn + j * 16 + (lane & 15);
                if (gn < 44) O[(size_t)gm * 44 + gn] = acc[i][j][q];
            }
        }
}

// ---------------------------------------------------------------------------
// Fused dt_proj + selective scan, LDS-staged (unchanged from R1).
// ---------------------------------------------------------------------------
__global__ __launch_bounds__(256)
void scan_fused_k(const float* __restrict__ xdbl, const float* __restrict__ xc,
                  const float* __restrict__ xz, const float* __restrict__ dtw,
                  const float* __restrict__ dtbias, const float* __restrict__ Alog,
                  const float* __restrict__ Dp, float* __restrict__ yg)
{
    __shared__ float sdt[L * 16];
    __shared__ float su [L * 16];
    __shared__ float sB [L * 16];
    __shared__ float sC [L * 16];
    __shared__ float sy [L * 16];

    const int blk = blockIdx.x;
    const int b = blk / (DI / 16);
    const int dc = blk % (DI / 16);
    const int tid = threadIdx.x;

    for (int idx = tid; idx < L * 16; idx += 256) {
        int t = idx >> 4, c = idx & 15;
        size_t row = (size_t)(b * L + t);
        const float* xr = xdbl + row * 44;
        sB[idx] = xr[12 + c];
        sC[idx] = xr[28 + c];
        su[idx] = xc[row * DI + dc * 16 + c];
        int d = dc * 16 + c;
        const float* wr = dtw + d * RK;
        float a = dtbias[d];
        #pragma unroll
        for (int k = 0; k < RK; ++k) a += xr[k] * wr[k];
        sdt[idx] = (a > 20.f) ? a : log1pf(expf(a));
    }
    __syncthreads();

    const int nl = tid & 15;
    const int dl = tid >> 4;
    const int d = dc * 16 + dl;
    const float Acoef = -expf(Alog[d * NS + nl]);
    const float Dv = Dp[d];
    float h = 0.f;
    #pragma unroll 4
    for (int t = 0; t < L; ++t) {
        float dtv = sdt[t * 16 + dl];
        float u   = su [t * 16 + dl];
        float Bv  = sB [t * 16 + nl];
        float Cv  = sC [t * 16 + nl];
        float dA = expf(dtv * Acoef);
        h = dA * h + (dtv * u) * Bv;
        float p = h * Cv;
        p += __shfl_xor(p, 8, 16);
        p += __shfl_xor(p, 4, 16);
        p += __shfl_xor(p, 2, 16);
        p += __shfl_xor(p, 1, 16);
        if (nl == 0) sy[t * 16 + dl] = p + u * Dv;
    }
    __syncthreads();

    for (int idx = tid; idx < L * 16; idx += 256) {
        int t = idx >> 4, c = idx & 15;
        size_t row = (size_t)(b * L + t);
        float z = xz[row * (2 * DI) + DI + dc * 16 + c];
        yg[row * DI + dc * 16 + c] = sy[idx] * siluf(z);
    }
}

// ---------------------------------------------------------------------------
// gemm3: residual += yg @ out_w^T   [1576,384]x[192,384]^T. grid (3, 25).
// ---------------------------------------------------------------------------
__global__ __launch_bounds__(256)
void gemm3_resid_k(const float* __restrict__ yg, const float* __restrict__ W,
                   float* __restrict__ residual)
{
    __shared__ __bf16 Xs[64][136];
    __shared__ __bf16 Ws[64][136];
    const int bm = blockIdx.y * 64;
    const int bn = blockIdx.x * 64;
    const int tid = threadIdx.x;
    const int lane = tid & 63, wv = tid >> 6;
    const int wm = (wv >> 1) * 32, wn = (wv & 1) * 32;
    const int lr = lane & 15, lk = (lane >> 4) * 8;
    f32x4 acc[2][2] = {};
    for (int k0 = 0; k0 < DI; k0 += 128) {
        for (int i = tid; i < 64 * 32; i += 256) {
            int r = i >> 5, k4 = (i & 31) * 4;
            int gm = bm + r;
            float4 v = {0.f, 0.f, 0.f, 0.f};
            if (gm < MROWS) v = *(const float4*)&yg[(size_t)gm * DI + k0 + k4];
            Xs[r][k4+0] = (__bf16)v.x; Xs[r][k4+1] = (__bf16)v.y;
            Xs[r][k4+2] = (__bf16)v.z; Xs[r][k4+3] = (__bf16)v.w;
        }
        for (int i = tid; i < 64 * 32; i += 256) {
            int r = i >> 5, k4 = (i & 31) * 4;
            float4 v = *(const float4*)&W[(size_t)(bn + r) * DI + k0 + k4];
            Ws[r][k4+0] = (__bf16)v.x; Ws[r][k4+1] = (__bf16)v.y;
            Ws[r][k4+2] = (__bf16)v.z; Ws[r][k4+3] = (__bf16)v.w;
        }
        __syncthreads();
        #pragma unroll
        for (int ks = 0; ks < 128; ks += 32) {
            bf16x8 a0 = *(const bf16x8*)&Xs[wm + lr][ks + lk];
            bf16x8 a1 = *(const bf16x8*)&Xs[wm + 16 + lr][ks + lk];
            bf16x8 b0 = *(const bf16x8*)&Ws[wn + lr][ks + lk];
            bf16x8 b1 = *(const bf16x8*)&Ws[wn + 16 + lr][ks + lk];
            acc[0][0] = __builtin_amdgcn_mfma_f32_16x16x32_bf16(a0, b0, acc[0][0], 0, 0, 0);
            acc[0][1] = __builtin_amdgcn_mfma_f32_16x16x32_bf16(a0, b1, acc[0][1], 0, 0, 0);
            acc[1][0] = __builtin_amdgcn_mfma_f32_16x16x32_bf16(a1, b0, acc[1][0], 0, 0, 0);
            acc[1][1] = __builtin_amdgcn_mfma_f32_16x16x32_bf16(a1, b1, acc[1][1], 0, 0, 0);
        }
        __syncthreads();
    }
    #pragma unroll
    for (int i = 0; i < 2; ++i)
        #pragma unroll
        for (int q = 0; q < 4; ++q) {
            int gm = bm + wm + i * 16 + (lane >> 4) * 4 + q;
            if (gm >= MROWS) continue;
            #pragma unroll
            for (int j = 0; j < 2; ++j) {
                int gn = bn + wn + j * 16 + (lane & 15);
                size_t off = (size_t)gm * DM + gn;
                residual[off] += acc[i][j][q];
            }
        }
}

// ---------------------------------------------------------------------------
// Final: rmsnorm(residual_final) at cls row then head GEMV. One block/batch.
// ---------------------------------------------------------------------------
__global__ __launch_bounds__(256)
void final_head_k(const float* __restrict__ residual, const float* __restrict__ nfw,
                  const float* __restrict__ hw, const float* __restrict__ hb,
                  float* __restrict__ out)
{
    int b = blockIdx.x;
    int tid = threadIdx.x;
    __shared__ float rowv[DM];
    __shared__ float wsum[4];
    size_t off = ((size_t)b * L + 98) * DM;
    float v = 0.f;
    if (tid < DM) v = residual[off + tid];
    float s = v * v;
    #pragma unroll
    for (int o = 32; o; o >>= 1) s += __shfl_down(s, o);
    if ((tid & 63) == 0) wsum[tid >> 6] = s;
    __syncthreads();
    float total = wsum[0] + wsum[1] + wsum[2] + wsum[3];
    float rs = rsqrtf(total * (1.f / DM) + 1e-5f);
    if (tid < DM) rowv[tid] = v * rs * nfw[tid];
    __syncthreads();
    for (int o = tid; o < 1000; o += 256) {
        float acc = hb[o];
        const float* w = hw + (size_t)o * DM;
        #pragma unroll 8
        for (int k = 0; k < DM; ++k) acc += w[k] * rowv[k];
        out[(size_t)b * 1000 + o] = acc;
    }
}

// ---------------------------------------------------------------------------
extern "C" void kernel_launch(void* const* d_in, const int* in_sizes, int n_in,
                              void* d_out, int out_size, void* d_ws, size_t ws_size,
                              hipStream_t stream)
{
    const float* x        = (const float*)d_in[0];
    const float* patch_w  = (const float*)d_in[1];
    const float* patch_b  = (const float*)d_in[2];
    const float* cls_tok  = (const float*)d_in[3];
    const float* pos_emb  = (const float*)d_in[4];
    const float* norm_w   = (const float*)d_in[5];
    const float* in_w     = (const float*)d_in[6];
    const float* conv_w   = (const float*)d_in[7];
    const float* conv_b   = (const float*)d_in[8];
    const float* xproj_w  = (const float*)d_in[9];
    const float* dt_w     = (const float*)d_in[10];
    const float* dt_b     = (const float*)d_in[11];
    const float* A_log    = (const float*)d_in[12];
    const float* D_par    = (const float*)d_in[13];
    const float* out_w    = (const float*)d_in[14];
    const float* norm_fw  = (const float*)d_in[15];
    const float* head_w   = (const float*)d_in[16];
    const float* head_b   = (const float*)d_in[17];

    float* ws = (float*)d_ws;
    float* residual = ws;  ws += (size_t)MROWS * DM;
    float* xzb      = ws;  ws += (size_t)MROWS * 2 * DI;
    float* xcb      = ws;  ws += (size_t)MROWS * DI;
    float* xdb      = ws;  ws += (size_t)MROWS * 44;
    float* ygb      = ws;  ws += (size_t)MROWS * DI;

    patch_gemm_k<<<dim3(3, 25), 256, 0, stream>>>(x, patch_w, patch_b, pos_emb, residual);
    cls_pos_k<<<1, DM, 0, stream>>>(cls_tok, pos_emb, residual);

    for (int l = 0; l < DEPTH_; ++l) {
        gemm1_rms_k<<<dim3(12, 25), 256, 0, stream>>>(residual, norm_w + l * DM,
                                                      in_w + (size_t)l * 2 * DI * DM, xzb);
        gemm2_conv_k<<<25, 256, 0, stream>>>(xzb, conv_w + l * DI * 4, conv_b + l * DI,
                                             xproj_w + (size_t)l * 44 * DI, xcb, xdb);
        scan_fused_k<<<B * (DI / 16), 256, 0, stream>>>(xdb, xcb, xzb,
                                                        dt_w + (size_t)l * DI * RK,
                                                        dt_b + l * DI,
                                                        A_log + (size_t)l * DI * NS,
                                                        D_par + l * DI, ygb);
        gemm3_resid_k<<<dim3(3, 25), 256, 0, stream>>>(ygb, out_w + (size_t)l * DM * DI,
                                                       residual);
    }
    final_head_k<<<B, 256, 0, stream>>>(residual, norm_fw, head_w, head_b, (float*)d_out);
}

// Round 4
// 2679.980 us; speedup vs baseline: 3.1283x; 1.8018x over previous
//
#include <hip/hip_runtime.h>
#include <hip/hip_bf16.h>
#include <math.h>

#define B 8
#define L 197
#define DM 192
#define DI 384
#define NS 16
#define RK 12
#define DEPTH_ 24
#define MROWS (B*L)   // 1576

typedef __bf16 bf16x8 __attribute__((ext_vector_type(8)));
typedef __bf16 bf16x4 __attribute__((ext_vector_type(4)));
typedef float  f32x4  __attribute__((ext_vector_type(4)));

__device__ __forceinline__ float siluf(float x) { return x / (1.f + expf(-x)); }

// ===========================================================================
// MFMA tile geometry (all GEMM kernels): 256 threads = 4 waves (2x2), block
// tile 64x64, per-wave 32x32 via 2x2 frags of mfma_f32_16x16x32_bf16.
// Frag load: row = lane&15, k = (lane>>4)*8.  D: col = lane&15,
// row = (lane>>4)*4 + reg  [m89-verified mapping].
// ===========================================================================

// ---------------------------------------------------------------------------
// Patch embed as GEMM: [1568 patches, 768] @ patch_w[192,768]^T. grid (3,25).
// ---------------------------------------------------------------------------
__global__ __launch_bounds__(256)
void patch_gemm_k(const float* __restrict__ x, const float* __restrict__ pw,
                  const float* __restrict__ pb, const float* __restrict__ pos,
                  float* __restrict__ residual)
{
    __shared__ __bf16 Xs[64][136];
    __shared__ __bf16 Ws[64][136];
    const int bm = blockIdx.y * 64;
    const int bn = blockIdx.x * 64;
    const int tid = threadIdx.x;
    const int lane = tid & 63, wv = tid >> 6;
    const int wm = (wv >> 1) * 32, wn = (wv & 1) * 32;
    const int lr = lane & 15, lk = (lane >> 4) * 8;
    f32x4 acc[2][2] = {};
    for (int k0 = 0; k0 < 768; k0 += 128) {
        for (int i = tid; i < 64 * 32; i += 256) {
            int r = i >> 5, k4 = (i & 31) * 4;
            int gm = bm + r;
            float4 v = {0.f, 0.f, 0.f, 0.f};
            if (gm < 1568) {
                int b = gm / 196, f = gm % 196;
                int py = f / 14, px = f % 14;
                int k = k0 + k4;
                int ci = k >> 8, rem = k & 255, ky = rem >> 4, kx = rem & 15;
                v = *(const float4*)&x[(((size_t)b * 3 + ci) * 224 + py * 16 + ky) * 224 + px * 16 + kx];
            }
            Xs[r][k4+0] = (__bf16)v.x; Xs[r][k4+1] = (__bf16)v.y;
            Xs[r][k4+2] = (__bf16)v.z; Xs[r][k4+3] = (__bf16)v.w;
        }
        for (int i = tid; i < 64 * 32; i += 256) {
            int r = i >> 5, k4 = (i & 31) * 4;
            float4 v = *(const float4*)&pw[(size_t)(bn + r) * 768 + k0 + k4];
            Ws[r][k4+0] = (__bf16)v.x; Ws[r][k4+1] = (__bf16)v.y;
            Ws[r][k4+2] = (__bf16)v.z; Ws[r][k4+3] = (__bf16)v.w;
        }
        __syncthreads();
        #pragma unroll
        for (int ks = 0; ks < 128; ks += 32) {
            bf16x8 a0 = *(const bf16x8*)&Xs[wm + lr][ks + lk];
            bf16x8 a1 = *(const bf16x8*)&Xs[wm + 16 + lr][ks + lk];
            bf16x8 b0 = *(const bf16x8*)&Ws[wn + lr][ks + lk];
            bf16x8 b1 = *(const bf16x8*)&Ws[wn + 16 + lr][ks + lk];
            acc[0][0] = __builtin_amdgcn_mfma_f32_16x16x32_bf16(a0, b0, acc[0][0], 0, 0, 0);
            acc[0][1] = __builtin_amdgcn_mfma_f32_16x16x32_bf16(a0, b1, acc[0][1], 0, 0, 0);
            acc[1][0] = __builtin_amdgcn_mfma_f32_16x16x32_bf16(a1, b0, acc[1][0], 0, 0, 0);
            acc[1][1] = __builtin_amdgcn_mfma_f32_16x16x32_bf16(a1, b1, acc[1][1], 0, 0, 0);
        }
        __syncthreads();
    }
    #pragma unroll
    for (int i = 0; i < 2; ++i) {
        #pragma unroll
        for (int q = 0; q < 4; ++q) {
            int gm = bm + wm + i * 16 + (lane >> 4) * 4 + q;
            if (gm >= 1568) continue;
            int b = gm / 196, f = gm % 196;
            int p = f + (f >= 98);
            #pragma unroll
            for (int j = 0; j < 2; ++j) {
                int gn = bn + wn + j * 16 + (lane & 15);
                residual[((size_t)b * L + p) * DM + gn] =
                    acc[i][j][q] + pb[gn] + pos[(size_t)p * DM + gn];
            }
        }
    }
}

__global__ __launch_bounds__(192)
void cls_pos_k(const float* __restrict__ cls, const float* __restrict__ pos,
               float* __restrict__ residual)
{
    int c = threadIdx.x;
    float v = cls[c] + pos[98 * DM + c];
    for (int b = 0; b < B; ++b)
        residual[((size_t)b * L + 98) * DM + c] = v;
}

// ---------------------------------------------------------------------------
// gemm1: xz = rmsnorm(residual)*nw @ in_w^T   [1576,192]x[768,192]^T.
// grid (12, 25).
// ---------------------------------------------------------------------------
__global__ __launch_bounds__(256)
void gemm1_rms_k(const float* __restrict__ residual, const float* __restrict__ nw,
                 const float* __restrict__ W, float* __restrict__ O)
{
    __shared__ __bf16 Xs[64][200];
    __shared__ __bf16 Ws[64][200];
    __shared__ float sinv[64];
    const int bm = blockIdx.y * 64;
    const int bn = blockIdx.x * 64;
    const int tid = threadIdx.x;
    const int lane = tid & 63, wv = tid >> 6;
    const int wm = (wv >> 1) * 32, wn = (wv & 1) * 32;
    const int lr = lane & 15, lk = (lane >> 4) * 8;
    {   // per-row inv rms: 4 threads/row, float4 interleaved
        int r = tid >> 2, q = tid & 3;
        int gm = bm + r;
        float s = 0.f;
        if (gm < MROWS) {
            const float4* xr = (const float4*)(residual + (size_t)gm * DM);
            #pragma unroll
            for (int i = 0; i < 12; ++i) {
                float4 v = xr[q + i * 4];
                s += v.x*v.x + v.y*v.y + v.z*v.z + v.w*v.w;
            }
        }
        s += __shfl_xor(s, 1, 4);
        s += __shfl_xor(s, 2, 4);
        if (q == 0) sinv[r] = rsqrtf(s * (1.f / DM) + 1e-5f);
    }
    __syncthreads();
    for (int i = tid; i < 64 * 48; i += 256) {
        int r = i / 48, k4 = (i % 48) * 4;
        int gm = bm + r;
        float4 v = {0.f, 0.f, 0.f, 0.f};
        if (gm < MROWS) v = *(const float4*)&residual[(size_t)gm * DM + k4];
        float sc = sinv[r];
        float4 w4 = *(const float4*)&nw[k4];
        Xs[r][k4+0] = (__bf16)(v.x * sc * w4.x);
        Xs[r][k4+1] = (__bf16)(v.y * sc * w4.y);
        Xs[r][k4+2] = (__bf16)(v.z * sc * w4.z);
        Xs[r][k4+3] = (__bf16)(v.w * sc * w4.w);
    }
    for (int i = tid; i < 64 * 48; i += 256) {
        int r = i / 48, k4 = (i % 48) * 4;
        float4 v = *(const float4*)&W[(size_t)(bn + r) * DM + k4];
        Ws[r][k4+0] = (__bf16)v.x; Ws[r][k4+1] = (__bf16)v.y;
        Ws[r][k4+2] = (__bf16)v.z; Ws[r][k4+3] = (__bf16)v.w;
    }
    __syncthreads();
    f32x4 acc[2][2] = {};
    #pragma unroll
    for (int ks = 0; ks < 192; ks += 32) {
        bf16x8 a0 = *(const bf16x8*)&Xs[wm + lr][ks + lk];
        bf16x8 a1 = *(const bf16x8*)&Xs[wm + 16 + lr][ks + lk];
        bf16x8 b0 = *(const bf16x8*)&Ws[wn + lr][ks + lk];
        bf16x8 b1 = *(const bf16x8*)&Ws[wn + 16 + lr][ks + lk];
        acc[0][0] = __builtin_amdgcn_mfma_f32_16x16x32_bf16(a0, b0, acc[0][0], 0, 0, 0);
        acc[0][1] = __builtin_amdgcn_mfma_f32_16x16x32_bf16(a0, b1, acc[0][1], 0, 0, 0);
        acc[1][0] = __builtin_amdgcn_mfma_f32_16x16x32_bf16(a1, b0, acc[1][0], 0, 0, 0);
        acc[1][1] = __builtin_amdgcn_mfma_f32_16x16x32_bf16(a1, b1, acc[1][1], 0, 0, 0);
    }
    #pragma unroll
    for (int i = 0; i < 2; ++i)
        #pragma unroll
        for (int q = 0; q < 4; ++q) {
            int gm = bm + wm + i * 16 + (lane >> 4) * 4 + q;
            if (gm >= MROWS) continue;
            #pragma unroll
            for (int j = 0; j < 2; ++j) {
                int gn = bn + wn + j * 16 + (lane & 15);
                O[(size_t)gm * (2 * DI) + gn] = acc[i][j][q];
            }
        }
}

// ---------------------------------------------------------------------------
// Depthwise causal conv1d + bias + silu, vectorized x4. Writes fp32 xc (for
// the scan) and bf16 xcb16 (for gemm2 staging). grid 591x256 covers exactly
// MROWS*DI/4 elements.
// ---------------------------------------------------------------------------
__global__ __launch_bounds__(256)
void conv_silu_k(const float* __restrict__ xz, const float* __restrict__ cw,
                 const float* __restrict__ cb, float* __restrict__ xc,
                 __bf16* __restrict__ xcb16)
{
    int idx4 = (blockIdx.x * 256 + threadIdx.x) * 4;
    if (idx4 >= MROWS * DI) return;
    int d = idx4 % DI;
    int row = idx4 / DI;
    int t = row % L;
    float a0 = cb[d], a1 = cb[d+1], a2 = cb[d+2], a3 = cb[d+3];
    #pragma unroll
    for (int j = 0; j < 4; ++j) {
        int tt = t - 3 + j;
        if (tt >= 0) {
            float4 v = *(const float4*)&xz[(size_t)(row - 3 + j) * (2 * DI) + d];
            a0 += v.x * cw[(d+0) * 4 + j];
            a1 += v.y * cw[(d+1) * 4 + j];
            a2 += v.z * cw[(d+2) * 4 + j];
            a3 += v.w * cw[(d+3) * 4 + j];
        }
    }
    float4 o = {siluf(a0), siluf(a1), siluf(a2), siluf(a3)};
    *(float4*)&xc[idx4] = o;
    bf16x4 h;
    h[0] = (__bf16)o.x; h[1] = (__bf16)o.y; h[2] = (__bf16)o.z; h[3] = (__bf16)o.w;
    *(bf16x4*)&xcb16[idx4] = h;
}

// ---------------------------------------------------------------------------
// gemm2: x_dbl_partial[kh] = xc_bf16[:, kh*192:(kh+1)*192] @ W[:, same]^T.
// grid (2, 25): K split in two, partials summed inside the scan kernel.
// Single staged K=192 pass, no k0 loop.
// ---------------------------------------------------------------------------
__global__ __launch_bounds__(256)
void gemm2_k(const __bf16* __restrict__ xcb16, const float* __restrict__ W,
             float* __restrict__ Op)
{
    __shared__ __bf16 Xs[64][200];
    __shared__ __bf16 Ws[64][200];
    const int kh = blockIdx.x;
    const int k0 = kh * 192;
    const int bm = blockIdx.y * 64;
    const int tid = threadIdx.x;
    const int lane = tid & 63, wv = tid >> 6;
    const int wm = (wv >> 1) * 32, wn = (wv & 1) * 32;
    const int lr = lane & 15, lk = (lane >> 4) * 8;
    float* Out = Op + (size_t)kh * MROWS * 44;

    for (int i = tid; i < 64 * 24; i += 256) {
        int r = i / 24, c8 = (i % 24) * 8;
        int gm = bm + r;
        bf16x8 v = {};
        if (gm < MROWS) v = *(const bf16x8*)&xcb16[(size_t)gm * DI + k0 + c8];
        *(bf16x8*)&Xs[r][c8] = v;
    }
    for (int i = tid; i < 64 * 48; i += 256) {
        int r = i / 48, c4 = (i % 48) * 4;
        float4 v = {0.f, 0.f, 0.f, 0.f};
        if (r < 44) v = *(const float4*)&W[(size_t)r * DI + k0 + c4];
        Ws[r][c4+0] = (__bf16)v.x; Ws[r][c4+1] = (__bf16)v.y;
        Ws[r][c4+2] = (__bf16)v.z; Ws[r][c4+3] = (__bf16)v.w;
    }
    __syncthreads();
    f32x4 acc[2][2] = {};
    #pragma unroll
    for (int ks = 0; ks < 192; ks += 32) {
        bf16x8 a0 = *(const bf16x8*)&Xs[wm + lr][ks + lk];
        bf16x8 a1 = *(const bf16x8*)&Xs[wm + 16 + lr][ks + lk];
        bf16x8 b0 = *(const bf16x8*)&Ws[wn + lr][ks + lk];
        bf16x8 b1 = *(const bf16x8*)&Ws[wn + 16 + lr][ks + lk];
        acc[0][0] = __builtin_amdgcn_mfma_f32_16x16x32_bf16(a0, b0, acc[0][0], 0, 0, 0);
        acc[0][1] = __builtin_amdgcn_mfma_f32_16x16x32_bf16(a0, b1, acc[0][1], 0, 0, 0);
        acc[1][0] = __builtin_amdgcn_mfma_f32_16x16x32_bf16(a1, b0, acc[1][0], 0, 0, 0);
        acc[1][1] = __builtin_amdgcn_mfma_f32_16x16x32_bf16(a1, b1, acc[1][1], 0, 0, 0);
    }
    #pragma unroll
    for (int i = 0; i < 2; ++i)
        #pragma unroll
        for (int q = 0; q < 4; ++q) {
            int gm = bm + wm + i * 16 + (lane >> 4) * 4 + q;
            if (gm >= MROWS) continue;
            #pragma unroll
            for (int j = 0; j < 2; ++j) {
                int gn = wn + j * 16 + (lane & 15);
                if (gn < 44) Out[(size_t)gm * 44 + gn] = acc[i][j][q];
            }
        }
}

// ---------------------------------------------------------------------------
// Fused dt_proj + selective scan; stages sum the two gemm2 K-partials.
// ---------------------------------------------------------------------------
__global__ __launch_bounds__(256)
void scan_fused_k(const float* __restrict__ xdbp, const float* __restrict__ xc,
                  const float* __restrict__ xz, const float* __restrict__ dtw,
                  const float* __restrict__ dtbias, const float* __restrict__ Alog,
                  const float* __restrict__ Dp, float* __restrict__ yg)
{
    __shared__ float sdt[L * 16];
    __shared__ float su [L * 16];
    __shared__ float sB [L * 16];
    __shared__ float sC [L * 16];
    __shared__ float sy [L * 16];

    const int blk = blockIdx.x;
    const int b = blk / (DI / 16);
    const int dc = blk % (DI / 16);
    const int tid = threadIdx.x;
    const float* xdb0 = xdbp;
    const float* xdb1 = xdbp + (size_t)MROWS * 44;

    for (int idx = tid; idx < L * 16; idx += 256) {
        int t = idx >> 4, c = idx & 15;
        size_t row = (size_t)(b * L + t);
        const float* xr0 = xdb0 + row * 44;
        const float* xr1 = xdb1 + row * 44;
        sB[idx] = xr0[12 + c] + xr1[12 + c];
        sC[idx] = xr0[28 + c] + xr1[28 + c];
        su[idx] = xc[row * DI + dc * 16 + c];
        int d = dc * 16 + c;
        const float* wr = dtw + d * RK;
        float a = dtbias[d];
        #pragma unroll
        for (int k = 0; k < RK; ++k) a += (xr0[k] + xr1[k]) * wr[k];
        sdt[idx] = (a > 20.f) ? a : log1pf(expf(a));
    }
    __syncthreads();

    const int nl = tid & 15;
    const int dl = tid >> 4;
    const int d = dc * 16 + dl;
    const float Acoef = -expf(Alog[d * NS + nl]);
    const float Dv = Dp[d];
    float h = 0.f;
    #pragma unroll 4
    for (int t = 0; t < L; ++t) {
        float dtv = sdt[t * 16 + dl];
        float u   = su [t * 16 + dl];
        float Bv  = sB [t * 16 + nl];
        float Cv  = sC [t * 16 + nl];
        float dA = expf(dtv * Acoef);
        h = dA * h + (dtv * u) * Bv;
        float p = h * Cv;
        p += __shfl_xor(p, 8, 16);
        p += __shfl_xor(p, 4, 16);
        p += __shfl_xor(p, 2, 16);
        p += __shfl_xor(p, 1, 16);
        if (nl == 0) sy[t * 16 + dl] = p + u * Dv;
    }
    __syncthreads();

    for (int idx = tid; idx < L * 16; idx += 256) {
        int t = idx >> 4, c = idx & 15;
        size_t row = (size_t)(b * L + t);
        float z = xz[row * (2 * DI) + DI + dc * 16 + c];
        yg[row * DI + dc * 16 + c] = sy[idx] * siluf(z);
    }
}

// ---------------------------------------------------------------------------
// gemm3: residual += yg @ out_w^T   [1576,384]x[192,384]^T. grid (3, 25).
// ---------------------------------------------------------------------------
__global__ __launch_bounds__(256)
void gemm3_resid_k(const float* __restrict__ yg, const float* __restrict__ W,
                   float* __restrict__ residual)
{
    __shared__ __bf16 Xs[64][136];
    __shared__ __bf16 Ws[64][136];
    const int bm = blockIdx.y * 64;
    const int bn = blockIdx.x * 64;
    const int tid = threadIdx.x;
    const int lane = tid & 63, wv = tid >> 6;
    const int wm = (wv >> 1) * 32, wn = (wv & 1) * 32;
    const int lr = lane & 15, lk = (lane >> 4) * 8;
    f32x4 acc[2][2] = {};
    for (int k0 = 0; k0 < DI; k0 += 128) {
        for (int i = tid; i < 64 * 32; i += 256) {
            int r = i >> 5, k4 = (i & 31) * 4;
            int gm = bm + r;
            float4 v = {0.f, 0.f, 0.f, 0.f};
            if (gm < MROWS) v = *(const float4*)&yg[(size_t)gm * DI + k0 + k4];
            Xs[r][k4+0] = (__bf16)v.x; Xs[r][k4+1] = (__bf16)v.y;
            Xs[r][k4+2] = (__bf16)v.z; Xs[r][k4+3] = (__bf16)v.w;
        }
        for (int i = tid; i < 64 * 32; i += 256) {
            int r = i >> 5, k4 = (i & 31) * 4;
            float4 v = *(const float4*)&W[(size_t)(bn + r) * DI + k0 + k4];
            Ws[r][k4+0] = (__bf16)v.x; Ws[r][k4+1] = (__bf16)v.y;
            Ws[r][k4+2] = (__bf16)v.z; Ws[r][k4+3] = (__bf16)v.w;
        }
        __syncthreads();
        #pragma unroll
        for (int ks = 0; ks < 128; ks += 32) {
            bf16x8 a0 = *(const bf16x8*)&Xs[wm + lr][ks + lk];
            bf16x8 a1 = *(const bf16x8*)&Xs[wm + 16 + lr][ks + lk];
            bf16x8 b0 = *(const bf16x8*)&Ws[wn + lr][ks + lk];
            bf16x8 b1 = *(const bf16x8*)&Ws[wn + 16 + lr][ks + lk];
            acc[0][0] = __builtin_amdgcn_mfma_f32_16x16x32_bf16(a0, b0, acc[0][0], 0, 0, 0);
            acc[0][1] = __builtin_amdgcn_mfma_f32_16x16x32_bf16(a0, b1, acc[0][1], 0, 0, 0);
            acc[1][0] = __builtin_amdgcn_mfma_f32_16x16x32_bf16(a1, b0, acc[1][0], 0, 0, 0);
            acc[1][1] = __builtin_amdgcn_mfma_f32_16x16x32_bf16(a1, b1, acc[1][1], 0, 0, 0);
        }
        __syncthreads();
    }
    #pragma unroll
    for (int i = 0; i < 2; ++i)
        #pragma unroll
        for (int q = 0; q < 4; ++q) {
            int gm = bm + wm + i * 16 + (lane >> 4) * 4 + q;
            if (gm >= MROWS) continue;
            #pragma unroll
            for (int j = 0; j < 2; ++j) {
                int gn = bn + wn + j * 16 + (lane & 15);
                size_t off = (size_t)gm * DM + gn;
                residual[off] += acc[i][j][q];
            }
        }
}

// ---------------------------------------------------------------------------
// Final: rmsnorm(residual_final) at cls row then head GEMV. One block/batch.
// ---------------------------------------------------------------------------
__global__ __launch_bounds__(256)
void final_head_k(const float* __restrict__ residual, const float* __restrict__ nfw,
                  const float* __restrict__ hw, const float* __restrict__ hb,
                  float* __restrict__ out)
{
    int b = blockIdx.x;
    int tid = threadIdx.x;
    __shared__ float rowv[DM];
    __shared__ float wsum[4];
    size_t off = ((size_t)b * L + 98) * DM;
    float v = 0.f;
    if (tid < DM) v = residual[off + tid];
    float s = v * v;
    #pragma unroll
    for (int o = 32; o; o >>= 1) s += __shfl_down(s, o);
    if ((tid & 63) == 0) wsum[tid >> 6] = s;
    __syncthreads();
    float total = wsum[0] + wsum[1] + wsum[2] + wsum[3];
    float rs = rsqrtf(total * (1.f / DM) + 1e-5f);
    if (tid < DM) rowv[tid] = v * rs * nfw[tid];
    __syncthreads();
    for (int o = tid; o < 1000; o += 256) {
        float acc = hb[o];
        const float* w = hw + (size_t)o * DM;
        #pragma unroll 8
        for (int k = 0; k < DM; ++k) acc += w[k] * rowv[k];
        out[(size_t)b * 1000 + o] = acc;
    }
}

// ---------------------------------------------------------------------------
extern "C" void kernel_launch(void* const* d_in, const int* in_sizes, int n_in,
                              void* d_out, int out_size, void* d_ws, size_t ws_size,
                              hipStream_t stream)
{
    const float* x        = (const float*)d_in[0];
    const float* patch_w  = (const float*)d_in[1];
    const float* patch_b  = (const float*)d_in[2];
    const float* cls_tok  = (const float*)d_in[3];
    const float* pos_emb  = (const float*)d_in[4];
    const float* norm_w   = (const float*)d_in[5];
    const float* in_w     = (const float*)d_in[6];
    const float* conv_w   = (const float*)d_in[7];
    const float* conv_b   = (const float*)d_in[8];
    const float* xproj_w  = (const float*)d_in[9];
    const float* dt_w     = (const float*)d_in[10];
    const float* dt_b     = (const float*)d_in[11];
    const float* A_log    = (const float*)d_in[12];
    const float* D_par    = (const float*)d_in[13];
    const float* out_w    = (const float*)d_in[14];
    const float* norm_fw  = (const float*)d_in[15];
    const float* head_w   = (const float*)d_in[16];
    const float* head_b   = (const float*)d_in[17];

    float* ws = (float*)d_ws;
    float* residual = ws;  ws += (size_t)MROWS * DM;
    float* xzb      = ws;  ws += (size_t)MROWS * 2 * DI;
    float* xcb      = ws;  ws += (size_t)MROWS * DI;
    float* xdbp     = ws;  ws += (size_t)2 * MROWS * 44;
    float* ygb      = ws;  ws += (size_t)MROWS * DI;
    __bf16* xcb16   = (__bf16*)ws;  ws += (size_t)MROWS * DI / 2;

    patch_gemm_k<<<dim3(3, 25), 256, 0, stream>>>(x, patch_w, patch_b, pos_emb, residual);
    cls_pos_k<<<1, DM, 0, stream>>>(cls_tok, pos_emb, residual);

    for (int l = 0; l < DEPTH_; ++l) {
        gemm1_rms_k<<<dim3(12, 25), 256, 0, stream>>>(residual, norm_w + l * DM,
                                                      in_w + (size_t)l * 2 * DI * DM, xzb);
        conv_silu_k<<<591, 256, 0, stream>>>(xzb, conv_w + l * DI * 4, conv_b + l * DI,
                                             xcb, xcb16);
        gemm2_k<<<dim3(2, 25), 256, 0, stream>>>(xcb16, xproj_w + (size_t)l * 44 * DI, xdbp);
        scan_fused_k<<<B * (DI / 16), 256, 0, stream>>>(xdbp, xcb, xzb,
                                                        dt_w + (size_t)l * DI * RK,
                                                        dt_b + l * DI,
                                                        A_log + (size_t)l * DI * NS,
                                                        D_par + l * DI, ygb);
        gemm3_resid_k<<<dim3(3, 25), 256, 0, stream>>>(ygb, out_w + (size_t)l * DM * DI,
                                                       residual);
    }
    final_head_k<<<B, 256, 0, stream>>>(residual, norm_fw, head_w, head_b, (float*)d_out);
}

// Round 5
// 2059.120 us; speedup vs baseline: 4.0715x; 1.3015x over previous
//
#include <hip/hip_runtime.h>
#include <hip/hip_bf16.h>
#include <math.h>

#define B 8
#define L 197
#define DM 192
#define DI 384
#define NS 16
#define RK 12
#define DEPTH_ 24
#define MROWS (B*L)   // 1576

typedef __bf16 bf16x8 __attribute__((ext_vector_type(8)));
typedef __bf16 bf16x4 __attribute__((ext_vector_type(4)));
typedef float  f32x4  __attribute__((ext_vector_type(4)));

__device__ __forceinline__ float siluf(float x) { return x / (1.f + __expf(-x)); }

// DPP-based 16-lane row reduction (VALU-rate, no LDS pipe).
// 0xB1 quad_perm[1,0,3,2] (xor1), 0x4E quad_perm[2,3,0,1] (xor2),
// 0x141 row_half_mirror (xor within 8), 0x140 row_mirror (full 16 reverse).
template<int CTRL>
__device__ __forceinline__ float dpp_addf(float s) {
    int v = __builtin_amdgcn_mov_dpp(__builtin_bit_cast(int, s), CTRL, 0xF, 0xF, true);
    return s + __builtin_bit_cast(float, v);
}
__device__ __forceinline__ float row_sum16(float p) {
    p = dpp_addf<0xB1>(p);
    p = dpp_addf<0x4E>(p);
    p = dpp_addf<0x141>(p);
    p = dpp_addf<0x140>(p);
    return p;
}

// ===========================================================================
// MFMA tile geometry (all GEMM kernels): 256 threads = 4 waves (2x2), block
// tile 64x64, per-wave 32x32 via 2x2 frags of mfma_f32_16x16x32_bf16.
// Frag load: row = lane&15, k = (lane>>4)*8.  D: col = lane&15,
// row = (lane>>4)*4 + reg  [m89-verified mapping].
// ===========================================================================

// ---------------------------------------------------------------------------
// Patch embed as GEMM: [1568 patches, 768] @ patch_w[192,768]^T. grid (3,25).
// ---------------------------------------------------------------------------
__global__ __launch_bounds__(256)
void patch_gemm_k(const float* __restrict__ x, const float* __restrict__ pw,
                  const float* __restrict__ pb, const float* __restrict__ pos,
                  float* __restrict__ residual)
{
    __shared__ __bf16 Xs[64][136];
    __shared__ __bf16 Ws[64][136];
    const int bm = blockIdx.y * 64;
    const int bn = blockIdx.x * 64;
    const int tid = threadIdx.x;
    const int lane = tid & 63, wv = tid >> 6;
    const int wm = (wv >> 1) * 32, wn = (wv & 1) * 32;
    const int lr = lane & 15, lk = (lane >> 4) * 8;
    f32x4 acc[2][2] = {};
    for (int k0 = 0; k0 < 768; k0 += 128) {
        for (int i = tid; i < 64 * 32; i += 256) {
            int r = i >> 5, k4 = (i & 31) * 4;
            int gm = bm + r;
            float4 v = {0.f, 0.f, 0.f, 0.f};
            if (gm < 1568) {
                int b = gm / 196, f = gm % 196;
                int py = f / 14, px = f % 14;
                int k = k0 + k4;
                int ci = k >> 8, rem = k & 255, ky = rem >> 4, kx = rem & 15;
                v = *(const float4*)&x[(((size_t)b * 3 + ci) * 224 + py * 16 + ky) * 224 + px * 16 + kx];
            }
            Xs[r][k4+0] = (__bf16)v.x; Xs[r][k4+1] = (__bf16)v.y;
            Xs[r][k4+2] = (__bf16)v.z; Xs[r][k4+3] = (__bf16)v.w;
        }
        for (int i = tid; i < 64 * 32; i += 256) {
            int r = i >> 5, k4 = (i & 31) * 4;
            float4 v = *(const float4*)&pw[(size_t)(bn + r) * 768 + k0 + k4];
            Ws[r][k4+0] = (__bf16)v.x; Ws[r][k4+1] = (__bf16)v.y;
            Ws[r][k4+2] = (__bf16)v.z; Ws[r][k4+3] = (__bf16)v.w;
        }
        __syncthreads();
        #pragma unroll
        for (int ks = 0; ks < 128; ks += 32) {
            bf16x8 a0 = *(const bf16x8*)&Xs[wm + lr][ks + lk];
            bf16x8 a1 = *(const bf16x8*)&Xs[wm + 16 + lr][ks + lk];
            bf16x8 b0 = *(const bf16x8*)&Ws[wn + lr][ks + lk];
            bf16x8 b1 = *(const bf16x8*)&Ws[wn + 16 + lr][ks + lk];
            acc[0][0] = __builtin_amdgcn_mfma_f32_16x16x32_bf16(a0, b0, acc[0][0], 0, 0, 0);
            acc[0][1] = __builtin_amdgcn_mfma_f32_16x16x32_bf16(a0, b1, acc[0][1], 0, 0, 0);
            acc[1][0] = __builtin_amdgcn_mfma_f32_16x16x32_bf16(a1, b0, acc[1][0], 0, 0, 0);
            acc[1][1] = __builtin_amdgcn_mfma_f32_16x16x32_bf16(a1, b1, acc[1][1], 0, 0, 0);
        }
        __syncthreads();
    }
    #pragma unroll
    for (int i = 0; i < 2; ++i) {
        #pragma unroll
        for (int q = 0; q < 4; ++q) {
            int gm = bm + wm + i * 16 + (lane >> 4) * 4 + q;
            if (gm >= 1568) continue;
            int b = gm / 196, f = gm % 196;
            int p = f + (f >= 98);
            #pragma unroll
            for (int j = 0; j < 2; ++j) {
                int gn = bn + wn + j * 16 + (lane & 15);
                residual[((size_t)b * L + p) * DM + gn] =
                    acc[i][j][q] + pb[gn] + pos[(size_t)p * DM + gn];
            }
        }
    }
}

__global__ __launch_bounds__(192)
void cls_pos_k(const float* __restrict__ cls, const float* __restrict__ pos,
               float* __restrict__ residual)
{
    int c = threadIdx.x;
    float v = cls[c] + pos[98 * DM + c];
    for (int b = 0; b < B; ++b)
        residual[((size_t)b * L + 98) * DM + c] = v;
}

// ---------------------------------------------------------------------------
// gemm1: xz = rmsnorm(residual)*nw @ in_w^T   [1576,192]x[768,192]^T.
// grid (12, 25).
// ---------------------------------------------------------------------------
__global__ __launch_bounds__(256)
void gemm1_rms_k(const float* __restrict__ residual, const float* __restrict__ nw,
                 const float* __restrict__ W, float* __restrict__ O)
{
    __shared__ __bf16 Xs[64][200];
    __shared__ __bf16 Ws[64][200];
    __shared__ float sinv[64];
    const int bm = blockIdx.y * 64;
    const int bn = blockIdx.x * 64;
    const int tid = threadIdx.x;
    const int lane = tid & 63, wv = tid >> 6;
    const int wm = (wv >> 1) * 32, wn = (wv & 1) * 32;
    const int lr = lane & 15, lk = (lane >> 4) * 8;
    {   // per-row inv rms: 4 threads/row, float4 interleaved
        int r = tid >> 2, q = tid & 3;
        int gm = bm + r;
        float s = 0.f;
        if (gm < MROWS) {
            const float4* xr = (const float4*)(residual + (size_t)gm * DM);
            #pragma unroll
            for (int i = 0; i < 12; ++i) {
                float4 v = xr[q + i * 4];
                s += v.x*v.x + v.y*v.y + v.z*v.z + v.w*v.w;
            }
        }
        s += __shfl_xor(s, 1, 4);
        s += __shfl_xor(s, 2, 4);
        if (q == 0) sinv[r] = rsqrtf(s * (1.f / DM) + 1e-5f);
    }
    __syncthreads();
    for (int i = tid; i < 64 * 48; i += 256) {
        int r = i / 48, k4 = (i % 48) * 4;
        int gm = bm + r;
        float4 v = {0.f, 0.f, 0.f, 0.f};
        if (gm < MROWS) v = *(const float4*)&residual[(size_t)gm * DM + k4];
        float sc = sinv[r];
        float4 w4 = *(const float4*)&nw[k4];
        Xs[r][k4+0] = (__bf16)(v.x * sc * w4.x);
        Xs[r][k4+1] = (__bf16)(v.y * sc * w4.y);
        Xs[r][k4+2] = (__bf16)(v.z * sc * w4.z);
        Xs[r][k4+3] = (__bf16)(v.w * sc * w4.w);
    }
    for (int i = tid; i < 64 * 48; i += 256) {
        int r = i / 48, k4 = (i % 48) * 4;
        float4 v = *(const float4*)&W[(size_t)(bn + r) * DM + k4];
        Ws[r][k4+0] = (__bf16)v.x; Ws[r][k4+1] = (__bf16)v.y;
        Ws[r][k4+2] = (__bf16)v.z; Ws[r][k4+3] = (__bf16)v.w;
    }
    __syncthreads();
    f32x4 acc[2][2] = {};
    #pragma unroll
    for (int ks = 0; ks < 192; ks += 32) {
        bf16x8 a0 = *(const bf16x8*)&Xs[wm + lr][ks + lk];
        bf16x8 a1 = *(const bf16x8*)&Xs[wm + 16 + lr][ks + lk];
        bf16x8 b0 = *(const bf16x8*)&Ws[wn + lr][ks + lk];
        bf16x8 b1 = *(const bf16x8*)&Ws[wn + 16 + lr][ks + lk];
        acc[0][0] = __builtin_amdgcn_mfma_f32_16x16x32_bf16(a0, b0, acc[0][0], 0, 0, 0);
        acc[0][1] = __builtin_amdgcn_mfma_f32_16x16x32_bf16(a0, b1, acc[0][1], 0, 0, 0);
        acc[1][0] = __builtin_amdgcn_mfma_f32_16x16x32_bf16(a1, b0, acc[1][0], 0, 0, 0);
        acc[1][1] = __builtin_amdgcn_mfma_f32_16x16x32_bf16(a1, b1, acc[1][1], 0, 0, 0);
    }
    #pragma unroll
    for (int i = 0; i < 2; ++i)
        #pragma unroll
        for (int q = 0; q < 4; ++q) {
            int gm = bm + wm + i * 16 + (lane >> 4) * 4 + q;
            if (gm >= MROWS) continue;
            #pragma unroll
            for (int j = 0; j < 2; ++j) {
                int gn = bn + wn + j * 16 + (lane & 15);
                O[(size_t)gm * (2 * DI) + gn] = acc[i][j][q];
            }
        }
}

// ---------------------------------------------------------------------------
// Depthwise causal conv1d + bias + silu, vectorized x4. Writes fp32 xc (for
// the scan) and bf16 xcb16 (for gemm2 staging). grid 591x256.
// ---------------------------------------------------------------------------
__global__ __launch_bounds__(256)
void conv_silu_k(const float* __restrict__ xz, const float* __restrict__ cw,
                 const float* __restrict__ cb, float* __restrict__ xc,
                 __bf16* __restrict__ xcb16)
{
    int idx4 = (blockIdx.x * 256 + threadIdx.x) * 4;
    if (idx4 >= MROWS * DI) return;
    int d = idx4 % DI;
    int row = idx4 / DI;
    int t = row % L;
    float a0 = cb[d], a1 = cb[d+1], a2 = cb[d+2], a3 = cb[d+3];
    #pragma unroll
    for (int j = 0; j < 4; ++j) {
        int tt = t - 3 + j;
        if (tt >= 0) {
            float4 v = *(const float4*)&xz[(size_t)(row - 3 + j) * (2 * DI) + d];
            a0 += v.x * cw[(d+0) * 4 + j];
            a1 += v.y * cw[(d+1) * 4 + j];
            a2 += v.z * cw[(d+2) * 4 + j];
            a3 += v.w * cw[(d+3) * 4 + j];
        }
    }
    float4 o = {siluf(a0), siluf(a1), siluf(a2), siluf(a3)};
    *(float4*)&xc[idx4] = o;
    bf16x4 h;
    h[0] = (__bf16)o.x; h[1] = (__bf16)o.y; h[2] = (__bf16)o.z; h[3] = (__bf16)o.w;
    *(bf16x4*)&xcb16[idx4] = h;
}

// ---------------------------------------------------------------------------
// gemm2: x_dbl_partial[kh] = xc_bf16[:, kh*192:(kh+1)*192] @ W[:, same]^T.
// grid (2, 25): K split in two, partials summed inside the scan kernel.
// ---------------------------------------------------------------------------
__global__ __launch_bounds__(256)
void gemm2_k(const __bf16* __restrict__ xcb16, const float* __restrict__ W,
             float* __restrict__ Op)
{
    __shared__ __bf16 Xs[64][200];
    __shared__ __bf16 Ws[64][200];
    const int kh = blockIdx.x;
    const int k0 = kh * 192;
    const int bm = blockIdx.y * 64;
    const int tid = threadIdx.x;
    const int lane = tid & 63, wv = tid >> 6;
    const int wm = (wv >> 1) * 32, wn = (wv & 1) * 32;
    const int lr = lane & 15, lk = (lane >> 4) * 8;
    float* Out = Op + (size_t)kh * MROWS * 44;

    for (int i = tid; i < 64 * 24; i += 256) {
        int r = i / 24, c8 = (i % 24) * 8;
        int gm = bm + r;
        bf16x8 v = {};
        if (gm < MROWS) v = *(const bf16x8*)&xcb16[(size_t)gm * DI + k0 + c8];
        *(bf16x8*)&Xs[r][c8] = v;
    }
    for (int i = tid; i < 64 * 48; i += 256) {
        int r = i / 48, c4 = (i % 48) * 4;
        float4 v = {0.f, 0.f, 0.f, 0.f};
        if (r < 44) v = *(const float4*)&W[(size_t)r * DI + k0 + c4];
        Ws[r][c4+0] = (__bf16)v.x; Ws[r][c4+1] = (__bf16)v.y;
        Ws[r][c4+2] = (__bf16)v.z; Ws[r][c4+3] = (__bf16)v.w;
    }
    __syncthreads();
    f32x4 acc[2][2] = {};
    #pragma unroll
    for (int ks = 0; ks < 192; ks += 32) {
        bf16x8 a0 = *(const bf16x8*)&Xs[wm + lr][ks + lk];
        bf16x8 a1 = *(const bf16x8*)&Xs[wm + 16 + lr][ks + lk];
        bf16x8 b0 = *(const bf16x8*)&Ws[wn + lr][ks + lk];
        bf16x8 b1 = *(const bf16x8*)&Ws[wn + 16 + lr][ks + lk];
        acc[0][0] = __builtin_amdgcn_mfma_f32_16x16x32_bf16(a0, b0, acc[0][0], 0, 0, 0);
        acc[0][1] = __builtin_amdgcn_mfma_f32_16x16x32_bf16(a0, b1, acc[0][1], 0, 0, 0);
        acc[1][0] = __builtin_amdgcn_mfma_f32_16x16x32_bf16(a1, b0, acc[1][0], 0, 0, 0);
        acc[1][1] = __builtin_amdgcn_mfma_f32_16x16x32_bf16(a1, b1, acc[1][1], 0, 0, 0);
    }
    #pragma unroll
    for (int i = 0; i < 2; ++i)
        #pragma unroll
        for (int q = 0; q < 4; ++q) {
            int gm = bm + wm + i * 16 + (lane >> 4) * 4 + q;
            if (gm >= MROWS) continue;
            #pragma unroll
            for (int j = 0; j < 2; ++j) {
                int gn = wn + j * 16 + (lane & 15);
                if (gn < 44) Out[(size_t)gm * 44 + gn] = acc[i][j][q];
            }
        }
}

// ---------------------------------------------------------------------------
// Fused dt_proj + selective scan; stages sum the two gemm2 K-partials.
// Scan loop uses DPP row reduce + fast exp.
// ---------------------------------------------------------------------------
__global__ __launch_bounds__(256)
void scan_fused_k(const float* __restrict__ xdbp, const float* __restrict__ xc,
                  const float* __restrict__ xz, const float* __restrict__ dtw,
                  const float* __restrict__ dtbias, const float* __restrict__ Alog,
                  const float* __restrict__ Dp, float* __restrict__ yg)
{
    __shared__ float sdt[L * 16];
    __shared__ float su [L * 16];
    __shared__ float sB [L * 16];
    __shared__ float sC [L * 16];
    __shared__ float sy [L * 16];

    const int blk = blockIdx.x;
    const int b = blk / (DI / 16);
    const int dc = blk % (DI / 16);
    const int tid = threadIdx.x;
    const float* xdb0 = xdbp;
    const float* xdb1 = xdbp + (size_t)MROWS * 44;

    for (int idx = tid; idx < L * 16; idx += 256) {
        int t = idx >> 4, c = idx & 15;
        size_t row = (size_t)(b * L + t);
        const float* xr0 = xdb0 + row * 44;
        const float* xr1 = xdb1 + row * 44;
        sB[idx] = xr0[12 + c] + xr1[12 + c];
        sC[idx] = xr0[28 + c] + xr1[28 + c];
        su[idx] = xc[row * DI + dc * 16 + c];
        int d = dc * 16 + c;
        const float* wr = dtw + d * RK;
        float a = dtbias[d];
        #pragma unroll
        for (int k = 0; k < RK; ++k) a += (xr0[k] + xr1[k]) * wr[k];
        sdt[idx] = (a > 20.f) ? a : __logf(1.f + __expf(a));
    }
    __syncthreads();

    const int nl = tid & 15;
    const int dl = tid >> 4;
    const int d = dc * 16 + dl;
    const float Acoef = -__expf(Alog[d * NS + nl]);
    const float Dv = Dp[d];
    float h = 0.f;
    #pragma unroll 8
    for (int t = 0; t < L; ++t) {
        float dtv = sdt[t * 16 + dl];
        float u   = su [t * 16 + dl];
        float Bv  = sB [t * 16 + nl];
        float Cv  = sC [t * 16 + nl];
        float dA = __expf(dtv * Acoef);
        h = dA * h + (dtv * u) * Bv;
        float p = row_sum16(h * Cv);
        if (nl == 0) sy[t * 16 + dl] = p + u * Dv;
    }
    __syncthreads();

    for (int idx = tid; idx < L * 16; idx += 256) {
        int t = idx >> 4, c = idx & 15;
        size_t row = (size_t)(b * L + t);
        float z = xz[row * (2 * DI) + DI + dc * 16 + c];
        yg[row * DI + dc * 16 + c] = sy[idx] * siluf(z);
    }
}

// ---------------------------------------------------------------------------
// gemm3: residual += yg @ out_w^T   [1576,384]x[192,384]^T. grid (3, 25).
// ---------------------------------------------------------------------------
__global__ __launch_bounds__(256)
void gemm3_resid_k(const float* __restrict__ yg, const float* __restrict__ W,
                   float* __restrict__ residual)
{
    __shared__ __bf16 Xs[64][136];
    __shared__ __bf16 Ws[64][136];
    const int bm = blockIdx.y * 64;
    const int bn = blockIdx.x * 64;
    const int tid = threadIdx.x;
    const int lane = tid & 63, wv = tid >> 6;
    const int wm = (wv >> 1) * 32, wn = (wv & 1) * 32;
    const int lr = lane & 15, lk = (lane >> 4) * 8;
    f32x4 acc[2][2] = {};
    for (int k0 = 0; k0 < DI; k0 += 128) {
        for (int i = tid; i < 64 * 32; i += 256) {
            int r = i >> 5, k4 = (i & 31) * 4;
            int gm = bm + r;
            float4 v = {0.f, 0.f, 0.f, 0.f};
            if (gm < MROWS) v = *(const float4*)&yg[(size_t)gm * DI + k0 + k4];
            Xs[r][k4+0] = (__bf16)v.x; Xs[r][k4+1] = (__bf16)v.y;
            Xs[r][k4+2] = (__bf16)v.z; Xs[r][k4+3] = (__bf16)v.w;
        }
        for (int i = tid; i < 64 * 32; i += 256) {
            int r = i >> 5, k4 = (i & 31) * 4;
            float4 v = *(const float4*)&W[(size_t)(bn + r) * DI + k0 + k4];
            Ws[r][k4+0] = (__bf16)v.x; Ws[r][k4+1] = (__bf16)v.y;
            Ws[r][k4+2] = (__bf16)v.z; Ws[r][k4+3] = (__bf16)v.w;
        }
        __syncthreads();
        #pragma unroll
        for (int ks = 0; ks < 128; ks += 32) {
            bf16x8 a0 = *(const bf16x8*)&Xs[wm + lr][ks + lk];
            bf16x8 a1 = *(const bf16x8*)&Xs[wm + 16 + lr][ks + lk];
            bf16x8 b0 = *(const bf16x8*)&Ws[wn + lr][ks + lk];
            bf16x8 b1 = *(const bf16x8*)&Ws[wn + 16 + lr][ks + lk];
            acc[0][0] = __builtin_amdgcn_mfma_f32_16x16x32_bf16(a0, b0, acc[0][0], 0, 0, 0);
            acc[0][1] = __builtin_amdgcn_mfma_f32_16x16x32_bf16(a0, b1, acc[0][1], 0, 0, 0);
            acc[1][0] = __builtin_amdgcn_mfma_f32_16x16x32_bf16(a1, b0, acc[1][0], 0, 0, 0);
            acc[1][1] = __builtin_amdgcn_mfma_f32_16x16x32_bf16(a1, b1, acc[1][1], 0, 0, 0);
        }
        __syncthreads();
    }
    #pragma unroll
    for (int i = 0; i < 2; ++i)
        #pragma unroll
        for (int q = 0; q < 4; ++q) {
            int gm = bm + wm + i * 16 + (lane >> 4) * 4 + q;
            if (gm >= MROWS) continue;
            #pragma unroll
            for (int j = 0; j < 2; ++j) {
                int gn = bn + wn + j * 16 + (lane & 15);
                size_t off = (size_t)gm * DM + gn;
                residual[off] += acc[i][j][q];
            }
        }
}

// ---------------------------------------------------------------------------
// Final: rmsnorm(residual_final) at cls row then head GEMV. One block/batch.
// ---------------------------------------------------------------------------
__global__ __launch_bounds__(256)
void final_head_k(const float* __restrict__ residual, const float* __restrict__ nfw,
                  const float* __restrict__ hw, const float* __restrict__ hb,
                  float* __restrict__ out)
{
    int b = blockIdx.x;
    int tid = threadIdx.x;
    __shared__ float rowv[DM];
    __shared__ float wsum[4];
    size_t off = ((size_t)b * L + 98) * DM;
    float v = 0.f;
    if (tid < DM) v = residual[off + tid];
    float s = v * v;
    #pragma unroll
    for (int o = 32; o; o >>= 1) s += __shfl_down(s, o);
    if ((tid & 63) == 0) wsum[tid >> 6] = s;
    __syncthreads();
    float total = wsum[0] + wsum[1] + wsum[2] + wsum[3];
    float rs = rsqrtf(total * (1.f / DM) + 1e-5f);
    if (tid < DM) rowv[tid] = v * rs * nfw[tid];
    __syncthreads();
    for (int o = tid; o < 1000; o += 256) {
        float acc = hb[o];
        const float* w = hw + (size_t)o * DM;
        #pragma unroll 8
        for (int k = 0; k < DM; ++k) acc += w[k] * rowv[k];
        out[(size_t)b * 1000 + o] = acc;
    }
}

// ---------------------------------------------------------------------------
extern "C" void kernel_launch(void* const* d_in, const int* in_sizes, int n_in,
                              void* d_out, int out_size, void* d_ws, size_t ws_size,
                              hipStream_t stream)
{
    const float* x        = (const float*)d_in[0];
    const float* patch_w  = (const float*)d_in[1];
    const float* patch_b  = (const float*)d_in[2];
    const float* cls_tok  = (const float*)d_in[3];
    const float* pos_emb  = (const float*)d_in[4];
    const float* norm_w   = (const float*)d_in[5];
    const float* in_w     = (const float*)d_in[6];
    const float* conv_w   = (const float*)d_in[7];
    const float* conv_b   = (const float*)d_in[8];
    const float* xproj_w  = (const float*)d_in[9];
    const float* dt_w     = (const float*)d_in[10];
    const float* dt_b     = (const float*)d_in[11];
    const float* A_log    = (const float*)d_in[12];
    const float* D_par    = (const float*)d_in[13];
    const float* out_w    = (const float*)d_in[14];
    const float* norm_fw  = (const float*)d_in[15];
    const float* head_w   = (const float*)d_in[16];
    const float* head_b   = (const float*)d_in[17];

    float* ws = (float*)d_ws;
    float* residual = ws;  ws += (size_t)MROWS * DM;
    float* xzb      = ws;  ws += (size_t)MROWS * 2 * DI;
    float* xcb      = ws;  ws += (size_t)MROWS * DI;
    float* xdbp     = ws;  ws += (size_t)2 * MROWS * 44;
    float* ygb      = ws;  ws += (size_t)MROWS * DI;
    __bf16* xcb16   = (__bf16*)ws;  ws += (size_t)MROWS * DI / 2;

    patch_gemm_k<<<dim3(3, 25), 256, 0, stream>>>(x, patch_w, patch_b, pos_emb, residual);
    cls_pos_k<<<1, DM, 0, stream>>>(cls_tok, pos_emb, residual);

    for (int l = 0; l < DEPTH_; ++l) {
        gemm1_rms_k<<<dim3(12, 25), 256, 0, stream>>>(residual, norm_w + l * DM,
                                                      in_w + (size_t)l * 2 * DI * DM, xzb);
        conv_silu_k<<<591, 256, 0, stream>>>(xzb, conv_w + l * DI * 4, conv_b + l * DI,
                                             xcb, xcb16);
        gemm2_k<<<dim3(2, 25), 256, 0, stream>>>(xcb16, xproj_w + (size_t)l * 44 * DI, xdbp);
        scan_fused_k<<<B * (DI / 16), 256, 0, stream>>>(xdbp, xcb, xzb,
                                                        dt_w + (size_t)l * DI * RK,
                                                        dt_b + l * DI,
                                                        A_log + (size_t)l * DI * NS,
                                                        D_par + l * DI, ygb);
        gemm3_resid_k<<<dim3(3, 25), 256, 0, stream>>>(ygb, out_w + (size_t)l * DM * DI,
                                                       residual);
    }
    final_head_k<<<B, 256, 0, stream>>>(residual, norm_fw, head_w, head_b, (float*)d_out);
}